// Round 8
// baseline (4323.508 us; speedup 1.0000x reference)
//
#include <hip/hip_runtime.h>

#define N_GENE 50000
#define N_PATH 20000
#define N_VACC 10000
#define N_TOT  80000
#define HID    128
#define E_PER  250000
#define OG 0
#define OP 50000
#define OV 70000

#define WLA_N 70000          // appnp columns (genes + pathways)
#define NBLK_E 245           // ceil(E_PER / 1024)
#define PBLK 2048            // persistent grid: 8 wg/CU x 256 CU, guaranteed by __launch_bounds__(128,4)
#define NGRP_BASE (N_TOT / 16)        // 5000 (exact)
#define NGRP_APP  (WLA_N / 16)        // 4375 (exact)

typedef _Float16  f16x8  __attribute__((ext_vector_type(8)));
typedef float     f32x4  __attribute__((ext_vector_type(4)));

__constant__ int c_segn[4] = {N_GENE, N_PATH, N_GENE, N_GENE};   // per-relation dst count
__constant__ int c_soff[4] = {OV, OG, OP, OG};                   // per-relation src global offset

struct Off4 { int* p[4]; };
struct Ei4 { const int* p[4]; };
struct AggSeg { const int* rows; const int* off; _Float16* out; int ldo; int n; };
struct Agg4 { AggSeg s[4]; };

// ---------------- CSR build: MSD 2-pass bucket sort (no global atomics) ----------------

__global__ void p1hist_kernel(Ei4 ei, int* __restrict__ bh)
{
    __shared__ int h[256];
    int t = threadIdx.x, bx = blockIdx.x, rel = blockIdx.y;
    h[t] = 0;
    __syncthreads();
    const int* dstp = ei.p[rel] + E_PER;
    int e0 = bx * 1024 + t * 4;
#pragma unroll
    for (int j = 0; j < 4; j++) {
        int e = e0 + j;
        if (e < E_PER) atomicAdd(&h[dstp[e] >> 8], 1);
    }
    __syncthreads();
    bh[((size_t)rel * NBLK_E + bx) * 256 + t] = h[t];
}

__global__ void p1scan_kernel(int* __restrict__ bh, int* __restrict__ tot)
{
    int t = threadIdx.x, hb = blockIdx.x, rel = blockIdx.y;
    int v = (t < NBLK_E) ? bh[((size_t)rel * NBLK_E + t) * 256 + hb] : 0;
    __shared__ int sh[256];
    sh[t] = v;
    __syncthreads();
    for (int d = 1; d < 256; d <<= 1) {
        int u = (t >= d) ? sh[t - d] : 0;
        __syncthreads();
        sh[t] += u;
        __syncthreads();
    }
    if (t < NBLK_E) bh[((size_t)rel * NBLK_E + t) * 256 + hb] = sh[t] - v;  // exclusive
    if (t == 255) tot[rel * 256 + hb] = sh[255];
}

__global__ void p1base_kernel(const int* __restrict__ tot, int* __restrict__ base)
{
    __shared__ int lt[1024];
    int t = threadIdx.x;
#pragma unroll
    for (int r = 0; r < 4; r++) lt[r * 256 + t] = tot[r * 256 + t];
    __syncthreads();
    if (t < 4) {
        int run = 0;
        for (int h = 0; h < 256; h++) { int v = lt[t * 256 + h]; lt[t * 256 + h] = run; run += v; }
    }
    __syncthreads();
#pragma unroll
    for (int r = 0; r < 4; r++) base[r * 256 + t] = lt[r * 256 + t];
}

__global__ void p1scatter_kernel(Ei4 ei, const int* __restrict__ bh, const int* __restrict__ base,
                                 unsigned long long* __restrict__ kp1)
{
    __shared__ int run[256];
    int t = threadIdx.x, bx = blockIdx.x, rel = blockIdx.y;
    run[t] = base[rel * 256 + t] + bh[((size_t)rel * NBLK_E + bx) * 256 + t];
    __syncthreads();
    const int* srcp = ei.p[rel];
    const int* dstp = srcp + E_PER;
    unsigned long long* out = kp1 + (size_t)rel * E_PER;
    int e0 = bx * 1024 + t * 4;
#pragma unroll
    for (int j = 0; j < 4; j++) {
        int e = e0 + j;
        if (e < E_PER) {
            int d = dstp[e], s = srcp[e];
            int pos = atomicAdd(&run[d >> 8], 1);
            out[pos] = ((unsigned long long)(unsigned)d << 32) | (unsigned)s;
        }
    }
}

__global__ void p2sort_kernel(const unsigned long long* __restrict__ kp1,
                              unsigned long long* __restrict__ kp0,
                              const int* __restrict__ tot, const int* __restrict__ base)
{
    int t = threadIdx.x, hb = blockIdx.x, rel = blockIdx.y;
    int start = base[rel * 256 + hb];
    int size  = tot[rel * 256 + hb];
    if (size == 0) return;
    const unsigned long long* in = kp1 + (size_t)rel * E_PER + start;
    unsigned long long* out = kp0 + (size_t)rel * E_PER;
    __shared__ int h[256];
    __shared__ int st[256];
    h[t] = 0;
    __syncthreads();
    for (int i = t; i < size; i += 256) atomicAdd(&h[(int)(in[i] >> 32) & 255], 1);
    __syncthreads();
    int v = h[t];
    for (int d = 1; d < 256; d <<= 1) {
        int u = (t >= d) ? h[t - d] : 0;
        __syncthreads();
        h[t] += u;
        __syncthreads();
    }
    st[t] = start + h[t] - v;   // global exclusive start of this low-byte bin
    __syncthreads();
    for (int i = t; i < size; i += 256) {
        unsigned long long it = in[i];
        int lb = (int)(it >> 32) & 255;
        int pos = atomicAdd(&st[lb], 1);
        out[pos] = it;
    }
}

// CSR offsets by boundary detection on the sorted list
__global__ void offbuild_kernel(const unsigned long long* __restrict__ kp0, Off4 op)
{
    int t = threadIdx.x, bx = blockIdx.x, rel = blockIdx.y;
    const unsigned long long* in = kp0 + (size_t)rel * E_PER;
    int* off = op.p[rel];
    int nd = c_segn[rel];
    int i0 = bx * 1024 + t * 4;
#pragma unroll
    for (int j = 0; j < 4; j++) {
        int i = i0 + j;
        if (i >= E_PER) continue;
        int d1 = (int)(in[i] >> 32);
        int d0 = (i == 0) ? -1 : (int)(in[i - 1] >> 32);
        for (int d = d0 + 1; d <= d1; d++) off[d] = i;
        if (i == E_PER - 1)
            for (int d = d1 + 1; d <= nd; d++) off[d] = E_PER;
    }
}

// also emits unified appnp offsets offA: genes offA[c]=r2+r3; paths offA[c]=500000+r1[c-OP]
__global__ void dinv_kernel(const int* __restrict__ r0, const int* __restrict__ r1,
                            const int* __restrict__ r2, const int* __restrict__ r3,
                            float* __restrict__ dinv, int* __restrict__ offA)
{
    int i = blockIdx.x * 256 + threadIdx.x;
    if (i >= N_TOT) return;
    int deg = 1;
    if (i < N_GENE) deg += (r0[i + 1] - r0[i]) + (r2[i + 1] - r2[i]) + (r3[i + 1] - r3[i]);
    else if (i < OV) { int k = i - OP; deg += r1[k + 1] - r1[k]; }
    dinv[i] = rsqrtf((float)deg);
    if (i <= N_GENE) offA[i] = r2[i] + r3[i];
    else if (i <= OV) offA[i] = 500000 + r1[i - OP];
}

// rows (global src ids) + packed (src, dinv[src]); merged-gene pkG positions are dst-sorted
// -> near-coalesced. rel1 -> pkAll[500000+i]; rel2 -> pkAll[i+off3[d]]; rel3 -> pkAll[i+off2[d+1]].
__global__ void emit_kernel(const unsigned long long* __restrict__ kp0,
                            const float* __restrict__ dinv,
                            const int* __restrict__ off2, const int* __restrict__ off3,
                            Off4 rp, int2* __restrict__ pkAll)
{
    int t = threadIdx.x, bx = blockIdx.x, rel = blockIdx.y;
    const unsigned long long* in = kp0 + (size_t)rel * E_PER;
    int* rows = rp.p[rel];
    int2* pk1 = pkAll + 500000;
    int i0 = bx * 1024 + t * 4;
#pragma unroll
    for (int j = 0; j < 4; j++) {
        int i = i0 + j;
        if (i >= E_PER) continue;
        unsigned long long it = in[i];
        int d = (int)(it >> 32);
        int g = (int)(it & 0xFFFFFFFFu) + c_soff[rel];
        rows[i] = g;
        if (rel == 0) continue;
        int2 pv = make_int2(g, __float_as_int(dinv[g]));
        if (rel == 1) pk1[i] = pv;
        else if (rel == 2) pkAll[i + off3[d]] = pv;
        else pkAll[i + off2[d + 1]] = pv;
    }
}

// ---------------- gather kernels (8 lanes/node, 16 nodes/block = 128 threads) ----------------

__global__ void agg_all_kernel(Agg4 a, const _Float16* __restrict__ Hh)
{
    int seg = blockIdx.y;
    int t = threadIdx.x;
    int node = blockIdx.x * 16 + (t >> 3);
    if (node >= a.s[seg].n) return;
    int o0 = (t & 7) * 8;
    const int* rows = a.s[seg].rows;
    int s = a.s[seg].off[node], e = a.s[seg].off[node + 1];
    float A[16] = {};
    int i = s;
    for (; i + 4 <= e; i += 4) {
        int r0 = rows[i], r1 = rows[i + 1], r2 = rows[i + 2], r3 = rows[i + 3];
        const _Float16* b0 = &Hh[(size_t)r0 * HID + o0];
        const _Float16* b1 = &Hh[(size_t)r1 * HID + o0];
        const _Float16* b2 = &Hh[(size_t)r2 * HID + o0];
        const _Float16* b3 = &Hh[(size_t)r3 * HID + o0];
        f16x8 x0a = *(const f16x8*)b0, x0b = *(const f16x8*)(b0 + 64);
        f16x8 x1a = *(const f16x8*)b1, x1b = *(const f16x8*)(b1 + 64);
        f16x8 x2a = *(const f16x8*)b2, x2b = *(const f16x8*)(b2 + 64);
        f16x8 x3a = *(const f16x8*)b3, x3b = *(const f16x8*)(b3 + 64);
#pragma unroll
        for (int j = 0; j < 8; j++) {
            A[j]     += ((float)x0a[j] + (float)x1a[j]) + ((float)x2a[j] + (float)x3a[j]);
            A[j + 8] += ((float)x0b[j] + (float)x1b[j]) + ((float)x2b[j] + (float)x3b[j]);
        }
    }
    for (; i < e; i++) {
        const _Float16* b = &Hh[(size_t)rows[i] * HID + o0];
        f16x8 xa = *(const f16x8*)b, xb = *(const f16x8*)(b + 64);
#pragma unroll
        for (int j = 0; j < 8; j++) { A[j] += (float)xa[j]; A[j + 8] += (float)xb[j]; }
    }
    float inv = (e > s) ? 1.0f / (float)(e - s) : 0.0f;
    f16x8 oa, ob;
#pragma unroll
    for (int j = 0; j < 8; j++) { oa[j] = (_Float16)(A[j] * inv); ob[j] = (_Float16)(A[j + 8] * inv); }
    _Float16* out = a.s[seg].out + (size_t)node * a.s[seg].ldo + o0;
    *(f16x8*)out = oa;
    *(f16x8*)(out + 64) = ob;
}

__device__ __forceinline__ void gath8(const int2* __restrict__ pk, int s, int e, int o0,
                                      const _Float16* __restrict__ zin, float (&A)[16])
{
    int i = s;
    for (; i + 4 <= e; i += 4) {
        int2 p0 = pk[i], p1 = pk[i + 1], p2 = pk[i + 2], p3 = pk[i + 3];
        const _Float16* b0 = &zin[(size_t)p0.x * HID + o0];
        const _Float16* b1 = &zin[(size_t)p1.x * HID + o0];
        const _Float16* b2 = &zin[(size_t)p2.x * HID + o0];
        const _Float16* b3 = &zin[(size_t)p3.x * HID + o0];
        f16x8 x0a = *(const f16x8*)b0, x0b = *(const f16x8*)(b0 + 64);
        f16x8 x1a = *(const f16x8*)b1, x1b = *(const f16x8*)(b1 + 64);
        f16x8 x2a = *(const f16x8*)b2, x2b = *(const f16x8*)(b2 + 64);
        f16x8 x3a = *(const f16x8*)b3, x3b = *(const f16x8*)(b3 + 64);
        float w0 = __int_as_float(p0.y), w1 = __int_as_float(p1.y);
        float w2 = __int_as_float(p2.y), w3 = __int_as_float(p3.y);
#pragma unroll
        for (int j = 0; j < 8; j++) {
            A[j]     += ((float)x0a[j] * w0 + (float)x1a[j] * w1) + ((float)x2a[j] * w2 + (float)x3a[j] * w3);
            A[j + 8] += ((float)x0b[j] * w0 + (float)x1b[j] * w1) + ((float)x2b[j] * w2 + (float)x3b[j] * w3);
        }
    }
    for (; i < e; i++) {
        int2 p = pk[i];
        const _Float16* b = &zin[(size_t)p.x * HID + o0];
        f16x8 xa = *(const f16x8*)b, xb = *(const f16x8*)(b + 64);
        float w = __int_as_float(p.y);
#pragma unroll
        for (int j = 0; j < 8; j++) { A[j] += (float)xa[j] * w; A[j + 8] += (float)xb[j] * w; }
    }
}

// ---------------- persistent fused base + 8x APPNP (software grid barrier) ----------------
// All PBLK=2048 blocks co-resident (guaranteed: __launch_bounds__(128,4) => >=4 waves/SIMD
// => >=8 two-wave workgroups/CU; grid = 8*256). Barrier: monotonic agent-scope counter;
// __threadfence release + acquire spin gives cross-XCD L2 visibility (same scheme as
// ROCm's cooperative grid sync). Phase bodies are byte-identical to the round-7 kernels.

__device__ __forceinline__ void grid_barrier(unsigned* bar, unsigned target)
{
    __syncthreads();
    if (threadIdx.x == 0) {
        __threadfence();
        __hip_atomic_fetch_add(bar, 1u, __ATOMIC_RELEASE, __HIP_MEMORY_SCOPE_AGENT);
        while (__hip_atomic_load(bar, __ATOMIC_ACQUIRE, __HIP_MEMORY_SCOPE_AGENT) < target)
            __builtin_amdgcn_s_sleep(2);
    }
    __syncthreads();
}

__launch_bounds__(128, 4)
__global__ void appnp_fused_kernel(const _Float16* __restrict__ Hh,
                                   const int* __restrict__ r0rows, const int* __restrict__ r0off,
                                   const float* __restrict__ dinv,
                                   _Float16* __restrict__ base,
                                   _Float16* __restrict__ Z1, _Float16* __restrict__ Z2,
                                   const int* __restrict__ offA, const int2* __restrict__ pkAll,
                                   float* __restrict__ dout, unsigned* __restrict__ bar)
{
    int t = threadIdx.x;
    int o0 = (t & 7) * 8;

    // ---- phase 0: base = fp16(0.1*Hh + genes: 0.9*dinv*sum h_v); Z1 = Hh; vaccine -> dout ----
    for (int g = blockIdx.x; g < NGRP_BASE; g += gridDim.x) {
        int node = g * 16 + (t >> 3);
        size_t i0 = (size_t)node * HID + o0;
        size_t i1 = i0 + 64;
        f16x8 ha = *(const f16x8*)&Hh[i0];
        f16x8 hb = *(const f16x8*)&Hh[i1];
        if (node >= OV) {
            f32x4 oa0, oa1, ob0, ob1;
#pragma unroll
            for (int j = 0; j < 4; j++) {
                oa0[j] = (float)ha[j]; oa1[j] = (float)ha[j + 4];
                ob0[j] = (float)hb[j]; ob1[j] = (float)hb[j + 4];
            }
            *(f32x4*)&dout[i0] = oa0; *(f32x4*)&dout[i0 + 4] = oa1;
            *(f32x4*)&dout[i1] = ob0; *(f32x4*)&dout[i1 + 4] = ob1;
        } else {
            float A[16] = {};
            if (node < N_GENE) {
                int s = r0off[node], e = r0off[node + 1];
                int i = s;
                for (; i + 4 <= e; i += 4) {
                    int r0 = r0rows[i], r1 = r0rows[i + 1], r2 = r0rows[i + 2], r3 = r0rows[i + 3];
                    const _Float16* b0 = &Hh[(size_t)r0 * HID + o0];
                    const _Float16* b1 = &Hh[(size_t)r1 * HID + o0];
                    const _Float16* b2 = &Hh[(size_t)r2 * HID + o0];
                    const _Float16* b3 = &Hh[(size_t)r3 * HID + o0];
                    f16x8 x0a = *(const f16x8*)b0, x0b = *(const f16x8*)(b0 + 64);
                    f16x8 x1a = *(const f16x8*)b1, x1b = *(const f16x8*)(b1 + 64);
                    f16x8 x2a = *(const f16x8*)b2, x2b = *(const f16x8*)(b2 + 64);
                    f16x8 x3a = *(const f16x8*)b3, x3b = *(const f16x8*)(b3 + 64);
#pragma unroll
                    for (int j = 0; j < 8; j++) {
                        A[j]     += ((float)x0a[j] + (float)x1a[j]) + ((float)x2a[j] + (float)x3a[j]);
                        A[j + 8] += ((float)x0b[j] + (float)x1b[j]) + ((float)x2b[j] + (float)x3b[j]);
                    }
                }
                for (; i < e; i++) {
                    const _Float16* b = &Hh[(size_t)r0rows[i] * HID + o0];
                    f16x8 xa = *(const f16x8*)b, xb = *(const f16x8*)(b + 64);
#pragma unroll
                    for (int j = 0; j < 8; j++) { A[j] += (float)xa[j]; A[j + 8] += (float)xb[j]; }
                }
                float sc = 0.9f * dinv[node];
#pragma unroll
                for (int j = 0; j < 16; j++) A[j] *= sc;
            }
            f16x8 ba, bb;
#pragma unroll
            for (int j = 0; j < 8; j++) {
                ba[j] = (_Float16)(0.1f * (float)ha[j] + A[j]);
                bb[j] = (_Float16)(0.1f * (float)hb[j] + A[j + 8]);
            }
            *(f16x8*)&base[i0] = ba; *(f16x8*)&base[i1] = bb;
            *(f16x8*)&Z1[i0] = ha;   *(f16x8*)&Z1[i1] = hb;
        }
    }
    grid_barrier(bar, gridDim.x);

    // ---- phases 1..8: z' = 0.9*(D^-1/2 A D^-1/2 z) + base; last phase writes fp32 dout ----
    for (int it = 0; it < 8; ++it) {
        const _Float16* zin = (it & 1) ? Z2 : Z1;
        _Float16* zo = (it & 1) ? Z1 : Z2;
        bool last = (it == 7);
        for (int g = blockIdx.x; g < NGRP_APP; g += gridDim.x) {
            int c = g * 16 + (t >> 3);
            float A[16] = {};
            gath8(pkAll, offA[c], offA[c + 1], o0, zin, A);
            float dc = dinv[c];
            float d2 = dc * dc;
            size_t i0 = (size_t)c * HID + o0;
            size_t i1 = i0 + 64;
            f16x8 za = *(const f16x8*)&zin[i0], zb = *(const f16x8*)&zin[i1];
            f16x8 ba = *(const f16x8*)&base[i0], bb = *(const f16x8*)&base[i1];
            float ra[8], rb[8];
#pragma unroll
            for (int j = 0; j < 8; j++) {
                ra[j] = 0.9f * (dc * A[j]     + d2 * (float)za[j]) + (float)ba[j];
                rb[j] = 0.9f * (dc * A[j + 8] + d2 * (float)zb[j]) + (float)bb[j];
            }
            if (!last) {
                f16x8 oa, ob;
#pragma unroll
                for (int j = 0; j < 8; j++) { oa[j] = (_Float16)ra[j]; ob[j] = (_Float16)rb[j]; }
                *(f16x8*)&zo[i0] = oa;
                *(f16x8*)&zo[i1] = ob;
            } else {
                f32x4 oa0, oa1, ob0, ob1;
#pragma unroll
                for (int j = 0; j < 4; j++) {
                    oa0[j] = ra[j]; oa1[j] = ra[j + 4];
                    ob0[j] = rb[j]; ob1[j] = rb[j + 4];
                }
                *(f32x4*)&dout[i0] = oa0; *(f32x4*)&dout[i0 + 4] = oa1;
                *(f32x4*)&dout[i1] = ob0; *(f32x4*)&dout[i1 + 4] = ob1;
            }
        }
        if (!last) grid_barrier(bar, (unsigned)gridDim.x * (it + 2));
    }
}

// ---------------- weight prep (fp16 shadows) ----------------

__global__ void prep_all_kernel(const float* __restrict__ wg, const float* __restrict__ wp,
                                const float* __restrict__ wv,
                                _Float16* __restrict__ obg, _Float16* __restrict__ obp, _Float16* __restrict__ obv,
                                const float* __restrict__ wsl, const float* __restrict__ bsl,
                                const float* __restrict__ wsr,
                                _Float16* __restrict__ Wg0, _Float16* __restrict__ Wg1,
                                _Float16* __restrict__ Wp0, _Float16* __restrict__ Wp1,
                                float* __restrict__ bg0, float* __restrict__ bg1,
                                float* __restrict__ bp0, float* __restrict__ bp1)
{
    int y = blockIdx.y;
    int i = blockIdx.x * 256 + threadIdx.x;
    if (y == 0) {
        if (i < 32768) obg[i] = (_Float16)wg[i];
        if (i < 16384) obp[i] = (_Float16)wp[i];
        if (i < 8192)  obv[i] = (_Float16)wv[i];
        return;
    }
    int layer = y - 1;
    const float* WL = wsl + (size_t)layer * 4 * HID * HID;
    const float* WR = wsr + (size_t)layer * 4 * HID * HID;
    _Float16* Wg = layer ? Wg1 : Wg0;
    _Float16* Wp = layer ? Wp1 : Wp0;
    float* bg = layer ? bg1 : bg0;
    float* bp = layer ? bp1 : bp0;
    if (i < 128 * 512) {
        int nr = i >> 9, k = i & 511;
        float v;
        if (k < 128)      v = WL[0 * 16384 + nr * 128 + k];
        else if (k < 256) v = WL[2 * 16384 + nr * 128 + (k - 128)];
        else if (k < 384) v = WL[3 * 16384 + nr * 128 + (k - 256)];
        else {
            int kk = k - 384;
            v = WR[0 * 16384 + nr * 128 + kk] + WR[2 * 16384 + nr * 128 + kk] + WR[3 * 16384 + nr * 128 + kk];
        }
        Wg[i] = (_Float16)v;
    }
    if (i < 128 * 256) {
        int nr = i >> 8, k = i & 255;
        float v = (k < 128) ? WL[1 * 16384 + nr * 128 + k] : WR[1 * 16384 + nr * 128 + (k - 128)];
        Wp[i] = (_Float16)v;
    }
    if (i < 128) {
        const float* BL = bsl + (size_t)layer * 4 * HID;
        bg[i] = BL[0 * 128 + i] + BL[2 * 128 + i] + BL[3 * 128 + i];
        bp[i] = BL[1 * 128 + i];
    }
}

// ---------------- tiled MFMA GEMM, fp16, compile-time K (static unroll) ----------------

template<int KT, int K1, bool A_F32, bool SAGE>
__launch_bounds__(256)
__global__ void tgemm_kernel(const void* __restrict__ A1_, const _Float16* __restrict__ A2,
                             const _Float16* __restrict__ W, const float* __restrict__ bias,
                             float scale, _Float16* __restrict__ Hh, int M)
{
    __shared__ _Float16 lds[128 * 40];
    int t = threadIdx.x;
    int wave = t >> 6, lane = t & 63;
    int r = lane & 15, quad = lane >> 4;
    int mbase = blockIdx.x * 128 + wave * 32;
    int mm0 = min(mbase + r, M - 1);
    int mm1 = min(mbase + 16 + r, M - 1);
    const float* Af = (const float*)A1_;
    const _Float16* Ab = (const _Float16*)A1_;

    f32x4 acc[2][8];
#pragma unroll
    for (int s = 0; s < 2; s++)
#pragma unroll
        for (int n = 0; n < 8; n++) acc[s][n] = (f32x4){0.f, 0.f, 0.f, 0.f};

    int srow = t >> 1;
    int selt = (t & 1) * 16;

#pragma unroll
    for (int k0 = 0; k0 < KT; k0 += 32) {
        __syncthreads();
        {
            const _Float16* wsrc = W + (size_t)srow * KT + k0 + selt;
            f16x8 w0 = *(const f16x8*)wsrc;
            f16x8 w1 = *(const f16x8*)(wsrc + 8);
            *(f16x8*)&lds[srow * 40 + selt] = w0;
            *(f16x8*)&lds[srow * 40 + selt + 8] = w1;
        }
        f16x8 a0, a1;
        if constexpr (A_F32) {
            const float* p0 = Af + (size_t)mm0 * KT + k0 + quad * 8;
            const float* p1 = Af + (size_t)mm1 * KT + k0 + quad * 8;
            f32x4 x0 = *(const f32x4*)p0, x1 = *(const f32x4*)(p0 + 4);
            f32x4 y0 = *(const f32x4*)p1, y1 = *(const f32x4*)(p1 + 4);
#pragma unroll
            for (int j = 0; j < 4; j++) { a0[j] = (_Float16)x0[j]; a0[j + 4] = (_Float16)x1[j]; }
#pragma unroll
            for (int j = 0; j < 4; j++) { a1[j] = (_Float16)y0[j]; a1[j + 4] = (_Float16)y1[j]; }
        } else if (k0 < K1) {
            a0 = *(const f16x8*)(Ab + (size_t)mm0 * K1 + k0 + quad * 8);
            a1 = *(const f16x8*)(Ab + (size_t)mm1 * K1 + k0 + quad * 8);
        } else {
            a0 = *(const f16x8*)(A2 + (size_t)mm0 * 128 + (k0 - K1) + quad * 8);
            a1 = *(const f16x8*)(A2 + (size_t)mm1 * 128 + (k0 - K1) + quad * 8);
        }
        __syncthreads();
#pragma unroll
        for (int nt = 0; nt < 8; nt++) {
            f16x8 b = *(const f16x8*)&lds[(nt * 16 + r) * 40 + quad * 8];
            acc[0][nt] = __builtin_amdgcn_mfma_f32_16x16x32_f16(a0, b, acc[0][nt], 0, 0, 0);
            acc[1][nt] = __builtin_amdgcn_mfma_f32_16x16x32_f16(a1, b, acc[1][nt], 0, 0, 0);
        }
    }

#pragma unroll
    for (int sub = 0; sub < 2; sub++) {
#pragma unroll
        for (int nt = 0; nt < 8; nt++) {
            int n = nt * 16 + r;
            float bv = bias[n];
#pragma unroll
            for (int i = 0; i < 4; i++) {
                int row = mbase + sub * 16 + quad * 4 + i;
                if (row >= M) continue;
                size_t idx = (size_t)row * HID + n;
                float v;
                if constexpr (SAGE) v = fmaxf((float)Hh[idx] + (acc[sub][nt][i] + bv) * scale, 0.f);
                else                v = fmaxf(acc[sub][nt][i] + bv, 0.f);
                Hh[idx] = (_Float16)v;
            }
        }
    }
}

// ---------------- driver ----------------

extern "C" void kernel_launch(void* const* d_in, const int* in_sizes, int n_in,
                              void* d_out, int out_size, void* d_ws, size_t ws_size,
                              hipStream_t stream)
{
    (void)in_sizes; (void)n_in; (void)out_size; (void)ws_size;

    const float* x_gene = (const float*)d_in[0];
    const float* x_path = (const float*)d_in[1];
    const float* x_vacc = (const float*)d_in[2];
    const float* win_g  = (const float*)d_in[3];
    const float* bin_g  = (const float*)d_in[4];
    const float* win_p  = (const float*)d_in[5];
    const float* bin_p  = (const float*)d_in[6];
    const float* win_v  = (const float*)d_in[7];
    const float* bin_v  = (const float*)d_in[8];
    const float* wsl    = (const float*)d_in[9];
    const float* bsl    = (const float*)d_in[10];
    const float* wsr    = (const float*)d_in[11];
    const int* ei_tg  = (const int*)d_in[12];
    const int* ei_ing = (const int*)d_in[13];
    const int* ei_ct  = (const int*)d_in[14];
    const int* ei_ii  = (const int*)d_in[15];

    char* p = (char*)d_ws;
    auto alloc = [&](size_t b) { char* r = p; p += (b + 255) & ~((size_t)255); return r; };

    _Float16* Hh   = (_Float16*)alloc((size_t)N_TOT * HID * 2);
    _Float16* BASE = (_Float16*)alloc((size_t)OV * HID * 2);
    _Float16* Z1   = (_Float16*)alloc((size_t)OV * HID * 2);
    _Float16* Z2   = (_Float16*)alloc((size_t)OV * HID * 2);
    _Float16* AGG_G = (_Float16*)alloc((size_t)N_GENE * 384 * 2);
    _Float16* AGG_P = (_Float16*)alloc((size_t)N_PATH * 128 * 2);
    float* dinv   = (float*)alloc((size_t)N_TOT * 4);
    int* r_rows[4], *r_off[4];
    for (int r = 0; r < 4; r++) r_rows[r] = (int*)alloc((size_t)E_PER * 4);
    r_off[0] = (int*)alloc((size_t)(N_GENE + 1) * 4);
    r_off[1] = (int*)alloc((size_t)(N_PATH + 1) * 4);
    r_off[2] = (int*)alloc((size_t)(N_GENE + 1) * 4);
    r_off[3] = (int*)alloc((size_t)(N_GENE + 1) * 4);
    int* offA = (int*)alloc((size_t)(WLA_N + 1) * 4);
    int2* pkAll = (int2*)alloc((size_t)750000 * 8);   // [0,500000): merged gene cols; [500000,750000): pathway cols
    unsigned long long* kp0 = (unsigned long long*)alloc((size_t)4 * E_PER * 8);
    unsigned long long* kp1 = (unsigned long long*)alloc((size_t)4 * E_PER * 8);
    int* bh   = (int*)alloc((size_t)4 * NBLK_E * 256 * 4);
    int* tot  = (int*)alloc((size_t)4 * 256 * 4);
    int* basebuf = (int*)alloc((size_t)4 * 256 * 4);
    unsigned* bar = (unsigned*)alloc(256);
    _Float16* wh_g = (_Float16*)alloc((size_t)HID * 256 * 2);
    _Float16* wh_p = (_Float16*)alloc((size_t)HID * 128 * 2);
    _Float16* wh_v = (_Float16*)alloc((size_t)HID * 64 * 2);
    _Float16* Wg[2]; _Float16* Wp[2]; float* bg[2]; float* bp[2];
    for (int l = 0; l < 2; l++) {
        Wg[l] = (_Float16*)alloc((size_t)128 * 512 * 2);
        Wp[l] = (_Float16*)alloc((size_t)128 * 256 * 2);
        bg[l] = (float*)alloc(128 * 4);
        bp[l] = (float*)alloc(128 * 4);
    }

    const int TB_G = (N_GENE + 127) / 128;
    const int TB_P = (N_PATH + 127) / 128;
    const int TB_V = (N_VACC + 127) / 128;

    hipMemsetAsync(bar, 0, 8, stream);

    prep_all_kernel<<<dim3(256, 3), 256, 0, stream>>>(win_g, win_p, win_v, wh_g, wh_p, wh_v,
                                                      wsl, bsl, wsr, Wg[0], Wg[1], Wp[0], Wp[1],
                                                      bg[0], bg[1], bp[0], bp[1]);

    // --- CSR build via MSD 2-pass bucket sort (no global atomics, no memset) ---
    Ei4 e4;
    e4.p[0] = ei_tg; e4.p[1] = ei_ing; e4.p[2] = ei_ct; e4.p[3] = ei_ii;
    p1hist_kernel<<<dim3(NBLK_E, 4), 256, 0, stream>>>(e4, bh);
    p1scan_kernel<<<dim3(256, 4), 256, 0, stream>>>(bh, tot);
    p1base_kernel<<<1, 256, 0, stream>>>(tot, basebuf);
    p1scatter_kernel<<<dim3(NBLK_E, 4), 256, 0, stream>>>(e4, bh, basebuf, kp1);
    p2sort_kernel<<<dim3(256, 4), 256, 0, stream>>>(kp1, kp0, tot, basebuf);

    Off4 op;
    op.p[0] = r_off[0]; op.p[1] = r_off[1]; op.p[2] = r_off[2]; op.p[3] = r_off[3];
    offbuild_kernel<<<dim3(NBLK_E, 4), 256, 0, stream>>>(kp0, op);

    dinv_kernel<<<(N_TOT + 255) / 256, 256, 0, stream>>>(r_off[0], r_off[1], r_off[2], r_off[3], dinv, offA);

    Off4 rp;
    rp.p[0] = r_rows[0]; rp.p[1] = r_rows[1]; rp.p[2] = r_rows[2]; rp.p[3] = r_rows[3];
    emit_kernel<<<dim3(NBLK_E, 4), 256, 0, stream>>>(kp0, dinv, r_off[2], r_off[3], rp, pkAll);

    // --- input projections (templated, static K) ---
    tgemm_kernel<256, 256, true, false><<<TB_G, 256, 0, stream>>>(x_gene, nullptr, wh_g, bin_g, 1.f, Hh, N_GENE);
    tgemm_kernel<128, 128, true, false><<<TB_P, 256, 0, stream>>>(x_path, nullptr, wh_p, bin_p, 1.f,
                                                                  Hh + (size_t)OP * HID, N_PATH);
    tgemm_kernel< 64,  64, true, false><<<TB_V, 256, 0, stream>>>(x_vacc, nullptr, wh_v, bin_v, 1.f,
                                                                  Hh + (size_t)OV * HID, N_VACC);

    // --- 2 hetero-SAGE layers ---
    Agg4 ag;
    ag.s[0] = {r_rows[0], r_off[0], AGG_G + 0,   384, N_GENE};
    ag.s[1] = {r_rows[2], r_off[2], AGG_G + 128, 384, N_GENE};
    ag.s[2] = {r_rows[3], r_off[3], AGG_G + 256, 384, N_GENE};
    ag.s[3] = {r_rows[1], r_off[1], AGG_P,       128, N_PATH};
    for (int l = 0; l < 2; l++) {
        agg_all_kernel<<<dim3((N_GENE + 15) / 16, 4), 128, 0, stream>>>(ag, Hh);

        tgemm_kernel<512, 384, false, true><<<TB_G, 256, 0, stream>>>(AGG_G, Hh, Wg[l], bg[l],
                                                                      1.0f / 3.0f, Hh, N_GENE);
        tgemm_kernel<256, 128, false, true><<<TB_P, 256, 0, stream>>>(AGG_P, Hh + (size_t)OP * HID, Wp[l], bp[l],
                                                                      1.0f, Hh + (size_t)OP * HID, N_PATH);
    }

    // --- fused base + 8x APPNP (persistent, software grid barrier) ---
    float* dout = (float*)d_out;
    appnp_fused_kernel<<<PBLK, 128, 0, stream>>>(Hh, r_rows[0], r_off[0], dinv, BASE, Z1, Z2,
                                                 offA, pkAll, dout, bar);
}

// Round 9
// 2644.999 us; speedup vs baseline: 1.6346x; 1.6346x over previous
//
#include <hip/hip_runtime.h>

#define N_GENE 50000
#define N_PATH 20000
#define N_VACC 10000
#define N_TOT  80000
#define HID    128
#define E_PER  250000
#define OG 0
#define OP 50000
#define OV 70000

#define WLA_N 70000          // appnp columns (genes + pathways)
#define NBLK_E 245           // ceil(E_PER / 1024)
#define PBLK 2048            // persistent grid: 8 wg/CU x 256 CU, guaranteed by __launch_bounds__(128,4)
#define NGRP_BASE (N_TOT / 16)        // 5000 (exact)
#define NGRP_APP  (WLA_N / 16)        // 4375 (exact)

typedef _Float16  f16x8  __attribute__((ext_vector_type(8)));
typedef float     f32x4  __attribute__((ext_vector_type(4)));

__constant__ int c_segn[4] = {N_GENE, N_PATH, N_GENE, N_GENE};   // per-relation dst count
__constant__ int c_soff[4] = {OV, OG, OP, OG};                   // per-relation src global offset

struct Off4 { int* p[4]; };
struct Ei4 { const int* p[4]; };
struct AggSeg { const int* rows; const int* off; _Float16* out; int ldo; int n; };
struct Agg4 { AggSeg s[4]; };

// ---------------- CSR build: MSD 2-pass bucket sort (no global atomics) ----------------

__global__ void p1hist_kernel(Ei4 ei, int* __restrict__ bh)
{
    __shared__ int h[256];
    int t = threadIdx.x, bx = blockIdx.x, rel = blockIdx.y;
    h[t] = 0;
    __syncthreads();
    const int* dstp = ei.p[rel] + E_PER;
    int e0 = bx * 1024 + t * 4;
#pragma unroll
    for (int j = 0; j < 4; j++) {
        int e = e0 + j;
        if (e < E_PER) atomicAdd(&h[dstp[e] >> 8], 1);
    }
    __syncthreads();
    bh[((size_t)rel * NBLK_E + bx) * 256 + t] = h[t];
}

__global__ void p1scan_kernel(int* __restrict__ bh, int* __restrict__ tot)
{
    int t = threadIdx.x, hb = blockIdx.x, rel = blockIdx.y;
    int v = (t < NBLK_E) ? bh[((size_t)rel * NBLK_E + t) * 256 + hb] : 0;
    __shared__ int sh[256];
    sh[t] = v;
    __syncthreads();
    for (int d = 1; d < 256; d <<= 1) {
        int u = (t >= d) ? sh[t - d] : 0;
        __syncthreads();
        sh[t] += u;
        __syncthreads();
    }
    if (t < NBLK_E) bh[((size_t)rel * NBLK_E + t) * 256 + hb] = sh[t] - v;  // exclusive
    if (t == 255) tot[rel * 256 + hb] = sh[255];
}

__global__ void p1base_kernel(const int* __restrict__ tot, int* __restrict__ base)
{
    __shared__ int lt[1024];
    int t = threadIdx.x;
#pragma unroll
    for (int r = 0; r < 4; r++) lt[r * 256 + t] = tot[r * 256 + t];
    __syncthreads();
    if (t < 4) {
        int run = 0;
        for (int h = 0; h < 256; h++) { int v = lt[t * 256 + h]; lt[t * 256 + h] = run; run += v; }
    }
    __syncthreads();
#pragma unroll
    for (int r = 0; r < 4; r++) base[r * 256 + t] = lt[r * 256 + t];
}

__global__ void p1scatter_kernel(Ei4 ei, const int* __restrict__ bh, const int* __restrict__ base,
                                 unsigned long long* __restrict__ kp1)
{
    __shared__ int run[256];
    int t = threadIdx.x, bx = blockIdx.x, rel = blockIdx.y;
    run[t] = base[rel * 256 + t] + bh[((size_t)rel * NBLK_E + bx) * 256 + t];
    __syncthreads();
    const int* srcp = ei.p[rel];
    const int* dstp = srcp + E_PER;
    unsigned long long* out = kp1 + (size_t)rel * E_PER;
    int e0 = bx * 1024 + t * 4;
#pragma unroll
    for (int j = 0; j < 4; j++) {
        int e = e0 + j;
        if (e < E_PER) {
            int d = dstp[e], s = srcp[e];
            int pos = atomicAdd(&run[d >> 8], 1);
            out[pos] = ((unsigned long long)(unsigned)d << 32) | (unsigned)s;
        }
    }
}

__global__ void p2sort_kernel(const unsigned long long* __restrict__ kp1,
                              unsigned long long* __restrict__ kp0,
                              const int* __restrict__ tot, const int* __restrict__ base)
{
    int t = threadIdx.x, hb = blockIdx.x, rel = blockIdx.y;
    int start = base[rel * 256 + hb];
    int size  = tot[rel * 256 + hb];
    if (size == 0) return;
    const unsigned long long* in = kp1 + (size_t)rel * E_PER + start;
    unsigned long long* out = kp0 + (size_t)rel * E_PER;
    __shared__ int h[256];
    __shared__ int st[256];
    h[t] = 0;
    __syncthreads();
    for (int i = t; i < size; i += 256) atomicAdd(&h[(int)(in[i] >> 32) & 255], 1);
    __syncthreads();
    int v = h[t];
    for (int d = 1; d < 256; d <<= 1) {
        int u = (t >= d) ? h[t - d] : 0;
        __syncthreads();
        h[t] += u;
        __syncthreads();
    }
    st[t] = start + h[t] - v;   // global exclusive start of this low-byte bin
    __syncthreads();
    for (int i = t; i < size; i += 256) {
        unsigned long long it = in[i];
        int lb = (int)(it >> 32) & 255;
        int pos = atomicAdd(&st[lb], 1);
        out[pos] = it;
    }
}

// CSR offsets by boundary detection on the sorted list
__global__ void offbuild_kernel(const unsigned long long* __restrict__ kp0, Off4 op)
{
    int t = threadIdx.x, bx = blockIdx.x, rel = blockIdx.y;
    const unsigned long long* in = kp0 + (size_t)rel * E_PER;
    int* off = op.p[rel];
    int nd = c_segn[rel];
    int i0 = bx * 1024 + t * 4;
#pragma unroll
    for (int j = 0; j < 4; j++) {
        int i = i0 + j;
        if (i >= E_PER) continue;
        int d1 = (int)(in[i] >> 32);
        int d0 = (i == 0) ? -1 : (int)(in[i - 1] >> 32);
        for (int d = d0 + 1; d <= d1; d++) off[d] = i;
        if (i == E_PER - 1)
            for (int d = d1 + 1; d <= nd; d++) off[d] = E_PER;
    }
}

// also emits unified appnp offsets offA: genes offA[c]=r2+r3; paths offA[c]=500000+r1[c-OP]
__global__ void dinv_kernel(const int* __restrict__ r0, const int* __restrict__ r1,
                            const int* __restrict__ r2, const int* __restrict__ r3,
                            float* __restrict__ dinv, int* __restrict__ offA)
{
    int i = blockIdx.x * 256 + threadIdx.x;
    if (i >= N_TOT) return;
    int deg = 1;
    if (i < N_GENE) deg += (r0[i + 1] - r0[i]) + (r2[i + 1] - r2[i]) + (r3[i + 1] - r3[i]);
    else if (i < OV) { int k = i - OP; deg += r1[k + 1] - r1[k]; }
    dinv[i] = rsqrtf((float)deg);
    if (i <= N_GENE) offA[i] = r2[i] + r3[i];
    else if (i <= OV) offA[i] = 500000 + r1[i - OP];
}

// rows (global src ids) + packed (src, dinv[src]); merged-gene pkG positions are dst-sorted
// -> near-coalesced. rel1 -> pkAll[500000+i]; rel2 -> pkAll[i+off3[d]]; rel3 -> pkAll[i+off2[d+1]].
__global__ void emit_kernel(const unsigned long long* __restrict__ kp0,
                            const float* __restrict__ dinv,
                            const int* __restrict__ off2, const int* __restrict__ off3,
                            Off4 rp, int2* __restrict__ pkAll)
{
    int t = threadIdx.x, bx = blockIdx.x, rel = blockIdx.y;
    const unsigned long long* in = kp0 + (size_t)rel * E_PER;
    int* rows = rp.p[rel];
    int2* pk1 = pkAll + 500000;
    int i0 = bx * 1024 + t * 4;
#pragma unroll
    for (int j = 0; j < 4; j++) {
        int i = i0 + j;
        if (i >= E_PER) continue;
        unsigned long long it = in[i];
        int d = (int)(it >> 32);
        int g = (int)(it & 0xFFFFFFFFu) + c_soff[rel];
        rows[i] = g;
        if (rel == 0) continue;
        int2 pv = make_int2(g, __float_as_int(dinv[g]));
        if (rel == 1) pk1[i] = pv;
        else if (rel == 2) pkAll[i + off3[d]] = pv;
        else pkAll[i + off2[d + 1]] = pv;
    }
}

// ---------------- gather kernels (8 lanes/node, 16 nodes/block = 128 threads) ----------------

__global__ void agg_all_kernel(Agg4 a, const _Float16* __restrict__ Hh)
{
    int seg = blockIdx.y;
    int t = threadIdx.x;
    int node = blockIdx.x * 16 + (t >> 3);
    if (node >= a.s[seg].n) return;
    int o0 = (t & 7) * 8;
    const int* rows = a.s[seg].rows;
    int s = a.s[seg].off[node], e = a.s[seg].off[node + 1];
    float A[16] = {};
    int i = s;
    for (; i + 4 <= e; i += 4) {
        int r0 = rows[i], r1 = rows[i + 1], r2 = rows[i + 2], r3 = rows[i + 3];
        const _Float16* b0 = &Hh[(size_t)r0 * HID + o0];
        const _Float16* b1 = &Hh[(size_t)r1 * HID + o0];
        const _Float16* b2 = &Hh[(size_t)r2 * HID + o0];
        const _Float16* b3 = &Hh[(size_t)r3 * HID + o0];
        f16x8 x0a = *(const f16x8*)b0, x0b = *(const f16x8*)(b0 + 64);
        f16x8 x1a = *(const f16x8*)b1, x1b = *(const f16x8*)(b1 + 64);
        f16x8 x2a = *(const f16x8*)b2, x2b = *(const f16x8*)(b2 + 64);
        f16x8 x3a = *(const f16x8*)b3, x3b = *(const f16x8*)(b3 + 64);
#pragma unroll
        for (int j = 0; j < 8; j++) {
            A[j]     += ((float)x0a[j] + (float)x1a[j]) + ((float)x2a[j] + (float)x3a[j]);
            A[j + 8] += ((float)x0b[j] + (float)x1b[j]) + ((float)x2b[j] + (float)x3b[j]);
        }
    }
    for (; i < e; i++) {
        const _Float16* b = &Hh[(size_t)rows[i] * HID + o0];
        f16x8 xa = *(const f16x8*)b, xb = *(const f16x8*)(b + 64);
#pragma unroll
        for (int j = 0; j < 8; j++) { A[j] += (float)xa[j]; A[j + 8] += (float)xb[j]; }
    }
    float inv = (e > s) ? 1.0f / (float)(e - s) : 0.0f;
    f16x8 oa, ob;
#pragma unroll
    for (int j = 0; j < 8; j++) { oa[j] = (_Float16)(A[j] * inv); ob[j] = (_Float16)(A[j + 8] * inv); }
    _Float16* out = a.s[seg].out + (size_t)node * a.s[seg].ldo + o0;
    *(f16x8*)out = oa;
    *(f16x8*)(out + 64) = ob;
}

__device__ __forceinline__ void gath8(const int2* __restrict__ pk, int s, int e, int o0,
                                      const _Float16* __restrict__ zin, float (&A)[16])
{
    int i = s;
    for (; i + 4 <= e; i += 4) {
        int2 p0 = pk[i], p1 = pk[i + 1], p2 = pk[i + 2], p3 = pk[i + 3];
        const _Float16* b0 = &zin[(size_t)p0.x * HID + o0];
        const _Float16* b1 = &zin[(size_t)p1.x * HID + o0];
        const _Float16* b2 = &zin[(size_t)p2.x * HID + o0];
        const _Float16* b3 = &zin[(size_t)p3.x * HID + o0];
        f16x8 x0a = *(const f16x8*)b0, x0b = *(const f16x8*)(b0 + 64);
        f16x8 x1a = *(const f16x8*)b1, x1b = *(const f16x8*)(b1 + 64);
        f16x8 x2a = *(const f16x8*)b2, x2b = *(const f16x8*)(b2 + 64);
        f16x8 x3a = *(const f16x8*)b3, x3b = *(const f16x8*)(b3 + 64);
        float w0 = __int_as_float(p0.y), w1 = __int_as_float(p1.y);
        float w2 = __int_as_float(p2.y), w3 = __int_as_float(p3.y);
#pragma unroll
        for (int j = 0; j < 8; j++) {
            A[j]     += ((float)x0a[j] * w0 + (float)x1a[j] * w1) + ((float)x2a[j] * w2 + (float)x3a[j] * w3);
            A[j + 8] += ((float)x0b[j] * w0 + (float)x1b[j] * w1) + ((float)x2b[j] * w2 + (float)x3b[j] * w3);
        }
    }
    for (; i < e; i++) {
        int2 p = pk[i];
        const _Float16* b = &zin[(size_t)p.x * HID + o0];
        f16x8 xa = *(const f16x8*)b, xb = *(const f16x8*)(b + 64);
        float w = __int_as_float(p.y);
#pragma unroll
        for (int j = 0; j < 8; j++) { A[j] += (float)xa[j] * w; A[j + 8] += (float)xb[j] * w; }
    }
}

// ---------------- persistent fused base + 8x APPNP (software grid barrier) ----------------
// Round-8 lesson: ACQUIRE atomic load in the spin loop emits a cache-invalidate per poll;
// thousands of spinners continuously trashed every XCD's L1/L2 while stragglers computed
// (12x slowdown, VALUBusy 2%). Fix: arrive with RELEASE add (one wbl2), spin on RELAXED
// loads (no invalidate), then ONE __threadfence() (acquire/inv) after the spin exits —
// the fence-based-acquire pattern used by ROCm's cooperative grid sync.

__device__ __forceinline__ void grid_barrier(unsigned* bar, unsigned target)
{
    __syncthreads();
    if (threadIdx.x == 0) {
        __hip_atomic_fetch_add(bar, 1u, __ATOMIC_RELEASE, __HIP_MEMORY_SCOPE_AGENT);
        while (__hip_atomic_load(bar, __ATOMIC_RELAXED, __HIP_MEMORY_SCOPE_AGENT) < target)
            __builtin_amdgcn_s_sleep(8);
        __threadfence();   // acquire: single invalidate after all releases observed
    }
    __syncthreads();
}

__launch_bounds__(128, 4)
__global__ void appnp_fused_kernel(const _Float16* __restrict__ Hh,
                                   const int* __restrict__ r0rows, const int* __restrict__ r0off,
                                   const float* __restrict__ dinv,
                                   _Float16* __restrict__ base,
                                   _Float16* __restrict__ Z1, _Float16* __restrict__ Z2,
                                   const int* __restrict__ offA, const int2* __restrict__ pkAll,
                                   float* __restrict__ dout, unsigned* __restrict__ bar)
{
    int t = threadIdx.x;
    int o0 = (t & 7) * 8;

    // ---- phase 0: base = fp16(0.1*Hh + genes: 0.9*dinv*sum h_v); Z1 = Hh; vaccine -> dout ----
    for (int g = blockIdx.x; g < NGRP_BASE; g += gridDim.x) {
        int node = g * 16 + (t >> 3);
        size_t i0 = (size_t)node * HID + o0;
        size_t i1 = i0 + 64;
        f16x8 ha = *(const f16x8*)&Hh[i0];
        f16x8 hb = *(const f16x8*)&Hh[i1];
        if (node >= OV) {
            f32x4 oa0, oa1, ob0, ob1;
#pragma unroll
            for (int j = 0; j < 4; j++) {
                oa0[j] = (float)ha[j]; oa1[j] = (float)ha[j + 4];
                ob0[j] = (float)hb[j]; ob1[j] = (float)hb[j + 4];
            }
            *(f32x4*)&dout[i0] = oa0; *(f32x4*)&dout[i0 + 4] = oa1;
            *(f32x4*)&dout[i1] = ob0; *(f32x4*)&dout[i1 + 4] = ob1;
        } else {
            float A[16] = {};
            if (node < N_GENE) {
                int s = r0off[node], e = r0off[node + 1];
                int i = s;
                for (; i + 4 <= e; i += 4) {
                    int r0 = r0rows[i], r1 = r0rows[i + 1], r2 = r0rows[i + 2], r3 = r0rows[i + 3];
                    const _Float16* b0 = &Hh[(size_t)r0 * HID + o0];
                    const _Float16* b1 = &Hh[(size_t)r1 * HID + o0];
                    const _Float16* b2 = &Hh[(size_t)r2 * HID + o0];
                    const _Float16* b3 = &Hh[(size_t)r3 * HID + o0];
                    f16x8 x0a = *(const f16x8*)b0, x0b = *(const f16x8*)(b0 + 64);
                    f16x8 x1a = *(const f16x8*)b1, x1b = *(const f16x8*)(b1 + 64);
                    f16x8 x2a = *(const f16x8*)b2, x2b = *(const f16x8*)(b2 + 64);
                    f16x8 x3a = *(const f16x8*)b3, x3b = *(const f16x8*)(b3 + 64);
#pragma unroll
                    for (int j = 0; j < 8; j++) {
                        A[j]     += ((float)x0a[j] + (float)x1a[j]) + ((float)x2a[j] + (float)x3a[j]);
                        A[j + 8] += ((float)x0b[j] + (float)x1b[j]) + ((float)x2b[j] + (float)x3b[j]);
                    }
                }
                for (; i < e; i++) {
                    const _Float16* b = &Hh[(size_t)r0rows[i] * HID + o0];
                    f16x8 xa = *(const f16x8*)b, xb = *(const f16x8*)(b + 64);
#pragma unroll
                    for (int j = 0; j < 8; j++) { A[j] += (float)xa[j]; A[j + 8] += (float)xb[j]; }
                }
                float sc = 0.9f * dinv[node];
#pragma unroll
                for (int j = 0; j < 16; j++) A[j] *= sc;
            }
            f16x8 ba, bb;
#pragma unroll
            for (int j = 0; j < 8; j++) {
                ba[j] = (_Float16)(0.1f * (float)ha[j] + A[j]);
                bb[j] = (_Float16)(0.1f * (float)hb[j] + A[j + 8]);
            }
            *(f16x8*)&base[i0] = ba; *(f16x8*)&base[i1] = bb;
            *(f16x8*)&Z1[i0] = ha;   *(f16x8*)&Z1[i1] = hb;
        }
    }
    grid_barrier(bar, gridDim.x);

    // ---- phases 1..8: z' = 0.9*(D^-1/2 A D^-1/2 z) + base; last phase writes fp32 dout ----
    for (int it = 0; it < 8; ++it) {
        const _Float16* zin = (it & 1) ? Z2 : Z1;
        _Float16* zo = (it & 1) ? Z1 : Z2;
        bool last = (it == 7);
        for (int g = blockIdx.x; g < NGRP_APP; g += gridDim.x) {
            int c = g * 16 + (t >> 3);
            float A[16] = {};
            gath8(pkAll, offA[c], offA[c + 1], o0, zin, A);
            float dc = dinv[c];
            float d2 = dc * dc;
            size_t i0 = (size_t)c * HID + o0;
            size_t i1 = i0 + 64;
            f16x8 za = *(const f16x8*)&zin[i0], zb = *(const f16x8*)&zin[i1];
            f16x8 ba = *(const f16x8*)&base[i0], bb = *(const f16x8*)&base[i1];
            float ra[8], rb[8];
#pragma unroll
            for (int j = 0; j < 8; j++) {
                ra[j] = 0.9f * (dc * A[j]     + d2 * (float)za[j]) + (float)ba[j];
                rb[j] = 0.9f * (dc * A[j + 8] + d2 * (float)zb[j]) + (float)bb[j];
            }
            if (!last) {
                f16x8 oa, ob;
#pragma unroll
                for (int j = 0; j < 8; j++) { oa[j] = (_Float16)ra[j]; ob[j] = (_Float16)rb[j]; }
                *(f16x8*)&zo[i0] = oa;
                *(f16x8*)&zo[i1] = ob;
            } else {
                f32x4 oa0, oa1, ob0, ob1;
#pragma unroll
                for (int j = 0; j < 4; j++) {
                    oa0[j] = ra[j]; oa1[j] = ra[j + 4];
                    ob0[j] = rb[j]; ob1[j] = rb[j + 4];
                }
                *(f32x4*)&dout[i0] = oa0; *(f32x4*)&dout[i0 + 4] = oa1;
                *(f32x4*)&dout[i1] = ob0; *(f32x4*)&dout[i1 + 4] = ob1;
            }
        }
        if (!last) grid_barrier(bar, (unsigned)gridDim.x * (it + 2));
    }
}

// ---------------- weight prep (fp16 shadows) ----------------

__global__ void prep_all_kernel(const float* __restrict__ wg, const float* __restrict__ wp,
                                const float* __restrict__ wv,
                                _Float16* __restrict__ obg, _Float16* __restrict__ obp, _Float16* __restrict__ obv,
                                const float* __restrict__ wsl, const float* __restrict__ bsl,
                                const float* __restrict__ wsr,
                                _Float16* __restrict__ Wg0, _Float16* __restrict__ Wg1,
                                _Float16* __restrict__ Wp0, _Float16* __restrict__ Wp1,
                                float* __restrict__ bg0, float* __restrict__ bg1,
                                float* __restrict__ bp0, float* __restrict__ bp1)
{
    int y = blockIdx.y;
    int i = blockIdx.x * 256 + threadIdx.x;
    if (y == 0) {
        if (i < 32768) obg[i] = (_Float16)wg[i];
        if (i < 16384) obp[i] = (_Float16)wp[i];
        if (i < 8192)  obv[i] = (_Float16)wv[i];
        return;
    }
    int layer = y - 1;
    const float* WL = wsl + (size_t)layer * 4 * HID * HID;
    const float* WR = wsr + (size_t)layer * 4 * HID * HID;
    _Float16* Wg = layer ? Wg1 : Wg0;
    _Float16* Wp = layer ? Wp1 : Wp0;
    float* bg = layer ? bg1 : bg0;
    float* bp = layer ? bp1 : bp0;
    if (i < 128 * 512) {
        int nr = i >> 9, k = i & 511;
        float v;
        if (k < 128)      v = WL[0 * 16384 + nr * 128 + k];
        else if (k < 256) v = WL[2 * 16384 + nr * 128 + (k - 128)];
        else if (k < 384) v = WL[3 * 16384 + nr * 128 + (k - 256)];
        else {
            int kk = k - 384;
            v = WR[0 * 16384 + nr * 128 + kk] + WR[2 * 16384 + nr * 128 + kk] + WR[3 * 16384 + nr * 128 + kk];
        }
        Wg[i] = (_Float16)v;
    }
    if (i < 128 * 256) {
        int nr = i >> 8, k = i & 255;
        float v = (k < 128) ? WL[1 * 16384 + nr * 128 + k] : WR[1 * 16384 + nr * 128 + (k - 128)];
        Wp[i] = (_Float16)v;
    }
    if (i < 128) {
        const float* BL = bsl + (size_t)layer * 4 * HID;
        bg[i] = BL[0 * 128 + i] + BL[2 * 128 + i] + BL[3 * 128 + i];
        bp[i] = BL[1 * 128 + i];
    }
}

// ---------------- tiled MFMA GEMM, fp16, compile-time K (static unroll) ----------------

template<int KT, int K1, bool A_F32, bool SAGE>
__launch_bounds__(256)
__global__ void tgemm_kernel(const void* __restrict__ A1_, const _Float16* __restrict__ A2,
                             const _Float16* __restrict__ W, const float* __restrict__ bias,
                             float scale, _Float16* __restrict__ Hh, int M)
{
    __shared__ _Float16 lds[128 * 40];
    int t = threadIdx.x;
    int wave = t >> 6, lane = t & 63;
    int r = lane & 15, quad = lane >> 4;
    int mbase = blockIdx.x * 128 + wave * 32;
    int mm0 = min(mbase + r, M - 1);
    int mm1 = min(mbase + 16 + r, M - 1);
    const float* Af = (const float*)A1_;
    const _Float16* Ab = (const _Float16*)A1_;

    f32x4 acc[2][8];
#pragma unroll
    for (int s = 0; s < 2; s++)
#pragma unroll
        for (int n = 0; n < 8; n++) acc[s][n] = (f32x4){0.f, 0.f, 0.f, 0.f};

    int srow = t >> 1;
    int selt = (t & 1) * 16;

#pragma unroll
    for (int k0 = 0; k0 < KT; k0 += 32) {
        __syncthreads();
        {
            const _Float16* wsrc = W + (size_t)srow * KT + k0 + selt;
            f16x8 w0 = *(const f16x8*)wsrc;
            f16x8 w1 = *(const f16x8*)(wsrc + 8);
            *(f16x8*)&lds[srow * 40 + selt] = w0;
            *(f16x8*)&lds[srow * 40 + selt + 8] = w1;
        }
        f16x8 a0, a1;
        if constexpr (A_F32) {
            const float* p0 = Af + (size_t)mm0 * KT + k0 + quad * 8;
            const float* p1 = Af + (size_t)mm1 * KT + k0 + quad * 8;
            f32x4 x0 = *(const f32x4*)p0, x1 = *(const f32x4*)(p0 + 4);
            f32x4 y0 = *(const f32x4*)p1, y1 = *(const f32x4*)(p1 + 4);
#pragma unroll
            for (int j = 0; j < 4; j++) { a0[j] = (_Float16)x0[j]; a0[j + 4] = (_Float16)x1[j]; }
#pragma unroll
            for (int j = 0; j < 4; j++) { a1[j] = (_Float16)y0[j]; a1[j + 4] = (_Float16)y1[j]; }
        } else if (k0 < K1) {
            a0 = *(const f16x8*)(Ab + (size_t)mm0 * K1 + k0 + quad * 8);
            a1 = *(const f16x8*)(Ab + (size_t)mm1 * K1 + k0 + quad * 8);
        } else {
            a0 = *(const f16x8*)(A2 + (size_t)mm0 * 128 + (k0 - K1) + quad * 8);
            a1 = *(const f16x8*)(A2 + (size_t)mm1 * 128 + (k0 - K1) + quad * 8);
        }
        __syncthreads();
#pragma unroll
        for (int nt = 0; nt < 8; nt++) {
            f16x8 b = *(const f16x8*)&lds[(nt * 16 + r) * 40 + quad * 8];
            acc[0][nt] = __builtin_amdgcn_mfma_f32_16x16x32_f16(a0, b, acc[0][nt], 0, 0, 0);
            acc[1][nt] = __builtin_amdgcn_mfma_f32_16x16x32_f16(a1, b, acc[1][nt], 0, 0, 0);
        }
    }

#pragma unroll
    for (int sub = 0; sub < 2; sub++) {
#pragma unroll
        for (int nt = 0; nt < 8; nt++) {
            int n = nt * 16 + r;
            float bv = bias[n];
#pragma unroll
            for (int i = 0; i < 4; i++) {
                int row = mbase + sub * 16 + quad * 4 + i;
                if (row >= M) continue;
                size_t idx = (size_t)row * HID + n;
                float v;
                if constexpr (SAGE) v = fmaxf((float)Hh[idx] + (acc[sub][nt][i] + bv) * scale, 0.f);
                else                v = fmaxf(acc[sub][nt][i] + bv, 0.f);
                Hh[idx] = (_Float16)v;
            }
        }
    }
}

// ---------------- driver ----------------

extern "C" void kernel_launch(void* const* d_in, const int* in_sizes, int n_in,
                              void* d_out, int out_size, void* d_ws, size_t ws_size,
                              hipStream_t stream)
{
    (void)in_sizes; (void)n_in; (void)out_size; (void)ws_size;

    const float* x_gene = (const float*)d_in[0];
    const float* x_path = (const float*)d_in[1];
    const float* x_vacc = (const float*)d_in[2];
    const float* win_g  = (const float*)d_in[3];
    const float* bin_g  = (const float*)d_in[4];
    const float* win_p  = (const float*)d_in[5];
    const float* bin_p  = (const float*)d_in[6];
    const float* win_v  = (const float*)d_in[7];
    const float* bin_v  = (const float*)d_in[8];
    const float* wsl    = (const float*)d_in[9];
    const float* bsl    = (const float*)d_in[10];
    const float* wsr    = (const float*)d_in[11];
    const int* ei_tg  = (const int*)d_in[12];
    const int* ei_ing = (const int*)d_in[13];
    const int* ei_ct  = (const int*)d_in[14];
    const int* ei_ii  = (const int*)d_in[15];

    char* p = (char*)d_ws;
    auto alloc = [&](size_t b) { char* r = p; p += (b + 255) & ~((size_t)255); return r; };

    _Float16* Hh   = (_Float16*)alloc((size_t)N_TOT * HID * 2);
    _Float16* BASE = (_Float16*)alloc((size_t)OV * HID * 2);
    _Float16* Z1   = (_Float16*)alloc((size_t)OV * HID * 2);
    _Float16* Z2   = (_Float16*)alloc((size_t)OV * HID * 2);
    _Float16* AGG_G = (_Float16*)alloc((size_t)N_GENE * 384 * 2);
    _Float16* AGG_P = (_Float16*)alloc((size_t)N_PATH * 128 * 2);
    float* dinv   = (float*)alloc((size_t)N_TOT * 4);
    int* r_rows[4], *r_off[4];
    for (int r = 0; r < 4; r++) r_rows[r] = (int*)alloc((size_t)E_PER * 4);
    r_off[0] = (int*)alloc((size_t)(N_GENE + 1) * 4);
    r_off[1] = (int*)alloc((size_t)(N_PATH + 1) * 4);
    r_off[2] = (int*)alloc((size_t)(N_GENE + 1) * 4);
    r_off[3] = (int*)alloc((size_t)(N_GENE + 1) * 4);
    int* offA = (int*)alloc((size_t)(WLA_N + 1) * 4);
    int2* pkAll = (int2*)alloc((size_t)750000 * 8);   // [0,500000): merged gene cols; [500000,750000): pathway cols
    unsigned long long* kp0 = (unsigned long long*)alloc((size_t)4 * E_PER * 8);
    unsigned long long* kp1 = (unsigned long long*)alloc((size_t)4 * E_PER * 8);
    int* bh   = (int*)alloc((size_t)4 * NBLK_E * 256 * 4);
    int* tot  = (int*)alloc((size_t)4 * 256 * 4);
    int* basebuf = (int*)alloc((size_t)4 * 256 * 4);
    unsigned* bar = (unsigned*)alloc(256);
    _Float16* wh_g = (_Float16*)alloc((size_t)HID * 256 * 2);
    _Float16* wh_p = (_Float16*)alloc((size_t)HID * 128 * 2);
    _Float16* wh_v = (_Float16*)alloc((size_t)HID * 64 * 2);
    _Float16* Wg[2]; _Float16* Wp[2]; float* bg[2]; float* bp[2];
    for (int l = 0; l < 2; l++) {
        Wg[l] = (_Float16*)alloc((size_t)128 * 512 * 2);
        Wp[l] = (_Float16*)alloc((size_t)128 * 256 * 2);
        bg[l] = (float*)alloc(128 * 4);
        bp[l] = (float*)alloc(128 * 4);
    }

    const int TB_G = (N_GENE + 127) / 128;
    const int TB_P = (N_PATH + 127) / 128;
    const int TB_V = (N_VACC + 127) / 128;

    hipMemsetAsync(bar, 0, 8, stream);

    prep_all_kernel<<<dim3(256, 3), 256, 0, stream>>>(win_g, win_p, win_v, wh_g, wh_p, wh_v,
                                                      wsl, bsl, wsr, Wg[0], Wg[1], Wp[0], Wp[1],
                                                      bg[0], bg[1], bp[0], bp[1]);

    // --- CSR build via MSD 2-pass bucket sort (no global atomics, no memset) ---
    Ei4 e4;
    e4.p[0] = ei_tg; e4.p[1] = ei_ing; e4.p[2] = ei_ct; e4.p[3] = ei_ii;
    p1hist_kernel<<<dim3(NBLK_E, 4), 256, 0, stream>>>(e4, bh);
    p1scan_kernel<<<dim3(256, 4), 256, 0, stream>>>(bh, tot);
    p1base_kernel<<<1, 256, 0, stream>>>(tot, basebuf);
    p1scatter_kernel<<<dim3(NBLK_E, 4), 256, 0, stream>>>(e4, bh, basebuf, kp1);
    p2sort_kernel<<<dim3(256, 4), 256, 0, stream>>>(kp1, kp0, tot, basebuf);

    Off4 op;
    op.p[0] = r_off[0]; op.p[1] = r_off[1]; op.p[2] = r_off[2]; op.p[3] = r_off[3];
    offbuild_kernel<<<dim3(NBLK_E, 4), 256, 0, stream>>>(kp0, op);

    dinv_kernel<<<(N_TOT + 255) / 256, 256, 0, stream>>>(r_off[0], r_off[1], r_off[2], r_off[3], dinv, offA);

    Off4 rp;
    rp.p[0] = r_rows[0]; rp.p[1] = r_rows[1]; rp.p[2] = r_rows[2]; rp.p[3] = r_rows[3];
    emit_kernel<<<dim3(NBLK_E, 4), 256, 0, stream>>>(kp0, dinv, r_off[2], r_off[3], rp, pkAll);

    // --- input projections (templated, static K) ---
    tgemm_kernel<256, 256, true, false><<<TB_G, 256, 0, stream>>>(x_gene, nullptr, wh_g, bin_g, 1.f, Hh, N_GENE);
    tgemm_kernel<128, 128, true, false><<<TB_P, 256, 0, stream>>>(x_path, nullptr, wh_p, bin_p, 1.f,
                                                                  Hh + (size_t)OP * HID, N_PATH);
    tgemm_kernel< 64,  64, true, false><<<TB_V, 256, 0, stream>>>(x_vacc, nullptr, wh_v, bin_v, 1.f,
                                                                  Hh + (size_t)OV * HID, N_VACC);

    // --- 2 hetero-SAGE layers ---
    Agg4 ag;
    ag.s[0] = {r_rows[0], r_off[0], AGG_G + 0,   384, N_GENE};
    ag.s[1] = {r_rows[2], r_off[2], AGG_G + 128, 384, N_GENE};
    ag.s[2] = {r_rows[3], r_off[3], AGG_G + 256, 384, N_GENE};
    ag.s[3] = {r_rows[1], r_off[1], AGG_P,       128, N_PATH};
    for (int l = 0; l < 2; l++) {
        agg_all_kernel<<<dim3((N_GENE + 15) / 16, 4), 128, 0, stream>>>(ag, Hh);

        tgemm_kernel<512, 384, false, true><<<TB_G, 256, 0, stream>>>(AGG_G, Hh, Wg[l], bg[l],
                                                                      1.0f / 3.0f, Hh, N_GENE);
        tgemm_kernel<256, 128, false, true><<<TB_P, 256, 0, stream>>>(AGG_P, Hh + (size_t)OP * HID, Wp[l], bp[l],
                                                                      1.0f, Hh + (size_t)OP * HID, N_PATH);
    }

    // --- fused base + 8x APPNP (persistent, software grid barrier) ---
    float* dout = (float*)d_out;
    appnp_fused_kernel<<<PBLK, 128, 0, stream>>>(Hh, r_rows[0], r_off[0], dinv, BASE, Z1, Z2,
                                                 offA, pkAll, dout, bar);
}

// Round 10
// 668.268 us; speedup vs baseline: 6.4697x; 3.9580x over previous
//
#include <hip/hip_runtime.h>

#define N_GENE 50000
#define N_PATH 20000
#define N_VACC 10000
#define N_TOT  80000
#define HID    128
#define E_PER  250000
#define OG 0
#define OP 50000
#define OV 70000

#define WLA_N 70000          // appnp columns (genes + pathways)
#define NBLK_E 245           // ceil(E_PER / 1024)

typedef _Float16  f16x8  __attribute__((ext_vector_type(8)));
typedef float     f32x4  __attribute__((ext_vector_type(4)));

__constant__ int c_segn[4] = {N_GENE, N_PATH, N_GENE, N_GENE};   // per-relation dst count
__constant__ int c_soff[4] = {OV, OG, OP, OG};                   // per-relation src global offset

struct Off4 { int* p[4]; };
struct Ei4 { const int* p[4]; };
struct AggSeg { const int* rows; const int* off; _Float16* out; int ldo; int n; };
struct Agg4 { AggSeg s[4]; };

// ---------------- CSR build: MSD 2-pass bucket sort (no global atomics) ----------------

__global__ void p1hist_kernel(Ei4 ei, int* __restrict__ bh)
{
    __shared__ int h[256];
    int t = threadIdx.x, bx = blockIdx.x, rel = blockIdx.y;
    h[t] = 0;
    __syncthreads();
    const int* dstp = ei.p[rel] + E_PER;
    int e0 = bx * 1024 + t * 4;
#pragma unroll
    for (int j = 0; j < 4; j++) {
        int e = e0 + j;
        if (e < E_PER) atomicAdd(&h[dstp[e] >> 8], 1);
    }
    __syncthreads();
    bh[((size_t)rel * NBLK_E + bx) * 256 + t] = h[t];
}

__global__ void p1scan_kernel(int* __restrict__ bh, int* __restrict__ tot)
{
    int t = threadIdx.x, hb = blockIdx.x, rel = blockIdx.y;
    int v = (t < NBLK_E) ? bh[((size_t)rel * NBLK_E + t) * 256 + hb] : 0;
    __shared__ int sh[256];
    sh[t] = v;
    __syncthreads();
    for (int d = 1; d < 256; d <<= 1) {
        int u = (t >= d) ? sh[t - d] : 0;
        __syncthreads();
        sh[t] += u;
        __syncthreads();
    }
    if (t < NBLK_E) bh[((size_t)rel * NBLK_E + t) * 256 + hb] = sh[t] - v;  // exclusive
    if (t == 255) tot[rel * 256 + hb] = sh[255];
}

__global__ void p1base_kernel(const int* __restrict__ tot, int* __restrict__ base)
{
    __shared__ int lt[1024];
    int t = threadIdx.x;
#pragma unroll
    for (int r = 0; r < 4; r++) lt[r * 256 + t] = tot[r * 256 + t];
    __syncthreads();
    if (t < 4) {
        int run = 0;
        for (int h = 0; h < 256; h++) { int v = lt[t * 256 + h]; lt[t * 256 + h] = run; run += v; }
    }
    __syncthreads();
#pragma unroll
    for (int r = 0; r < 4; r++) base[r * 256 + t] = lt[r * 256 + t];
}

__global__ void p1scatter_kernel(Ei4 ei, const int* __restrict__ bh, const int* __restrict__ base,
                                 unsigned long long* __restrict__ kp1)
{
    __shared__ int run[256];
    int t = threadIdx.x, bx = blockIdx.x, rel = blockIdx.y;
    run[t] = base[rel * 256 + t] + bh[((size_t)rel * NBLK_E + bx) * 256 + t];
    __syncthreads();
    const int* srcp = ei.p[rel];
    const int* dstp = srcp + E_PER;
    unsigned long long* out = kp1 + (size_t)rel * E_PER;
    int e0 = bx * 1024 + t * 4;
#pragma unroll
    for (int j = 0; j < 4; j++) {
        int e = e0 + j;
        if (e < E_PER) {
            int d = dstp[e], s = srcp[e];
            int pos = atomicAdd(&run[d >> 8], 1);
            out[pos] = ((unsigned long long)(unsigned)d << 32) | (unsigned)s;
        }
    }
}

__global__ void p2sort_kernel(const unsigned long long* __restrict__ kp1,
                              unsigned long long* __restrict__ kp0,
                              const int* __restrict__ tot, const int* __restrict__ base)
{
    int t = threadIdx.x, hb = blockIdx.x, rel = blockIdx.y;
    int start = base[rel * 256 + hb];
    int size  = tot[rel * 256 + hb];
    if (size == 0) return;
    const unsigned long long* in = kp1 + (size_t)rel * E_PER + start;
    unsigned long long* out = kp0 + (size_t)rel * E_PER;
    __shared__ int h[256];
    __shared__ int st[256];
    h[t] = 0;
    __syncthreads();
    for (int i = t; i < size; i += 256) atomicAdd(&h[(int)(in[i] >> 32) & 255], 1);
    __syncthreads();
    int v = h[t];
    for (int d = 1; d < 256; d <<= 1) {
        int u = (t >= d) ? h[t - d] : 0;
        __syncthreads();
        h[t] += u;
        __syncthreads();
    }
    st[t] = start + h[t] - v;   // global exclusive start of this low-byte bin
    __syncthreads();
    for (int i = t; i < size; i += 256) {
        unsigned long long it = in[i];
        int lb = (int)(it >> 32) & 255;
        int pos = atomicAdd(&st[lb], 1);
        out[pos] = it;
    }
}

// CSR offsets by boundary detection on the sorted list
__global__ void offbuild_kernel(const unsigned long long* __restrict__ kp0, Off4 op)
{
    int t = threadIdx.x, bx = blockIdx.x, rel = blockIdx.y;
    const unsigned long long* in = kp0 + (size_t)rel * E_PER;
    int* off = op.p[rel];
    int nd = c_segn[rel];
    int i0 = bx * 1024 + t * 4;
#pragma unroll
    for (int j = 0; j < 4; j++) {
        int i = i0 + j;
        if (i >= E_PER) continue;
        int d1 = (int)(in[i] >> 32);
        int d0 = (i == 0) ? -1 : (int)(in[i - 1] >> 32);
        for (int d = d0 + 1; d <= d1; d++) off[d] = i;
        if (i == E_PER - 1)
            for (int d = d1 + 1; d <= nd; d++) off[d] = E_PER;
    }
}

// also emits unified appnp offsets offA: genes offA[c]=r2+r3; paths offA[c]=500000+r1[c-OP]
__global__ void dinv_kernel(const int* __restrict__ r0, const int* __restrict__ r1,
                            const int* __restrict__ r2, const int* __restrict__ r3,
                            float* __restrict__ dinv, int* __restrict__ offA)
{
    int i = blockIdx.x * 256 + threadIdx.x;
    if (i >= N_TOT) return;
    int deg = 1;
    if (i < N_GENE) deg += (r0[i + 1] - r0[i]) + (r2[i + 1] - r2[i]) + (r3[i + 1] - r3[i]);
    else if (i < OV) { int k = i - OP; deg += r1[k + 1] - r1[k]; }
    dinv[i] = rsqrtf((float)deg);
    if (i <= N_GENE) offA[i] = r2[i] + r3[i];
    else if (i <= OV) offA[i] = 500000 + r1[i - OP];
}

// rows (global src ids) + packed (src, dinv[src]); merged-gene pkG positions are dst-sorted
// -> near-coalesced. rel1 -> pkAll[500000+i]; rel2 -> pkAll[i+off3[d]]; rel3 -> pkAll[i+off2[d+1]].
__global__ void emit_kernel(const unsigned long long* __restrict__ kp0,
                            const float* __restrict__ dinv,
                            const int* __restrict__ off2, const int* __restrict__ off3,
                            Off4 rp, int2* __restrict__ pkAll)
{
    int t = threadIdx.x, bx = blockIdx.x, rel = blockIdx.y;
    const unsigned long long* in = kp0 + (size_t)rel * E_PER;
    int* rows = rp.p[rel];
    int2* pk1 = pkAll + 500000;
    int i0 = bx * 1024 + t * 4;
#pragma unroll
    for (int j = 0; j < 4; j++) {
        int i = i0 + j;
        if (i >= E_PER) continue;
        unsigned long long it = in[i];
        int d = (int)(it >> 32);
        int g = (int)(it & 0xFFFFFFFFu) + c_soff[rel];
        rows[i] = g;
        if (rel == 0) continue;
        int2 pv = make_int2(g, __float_as_int(dinv[g]));
        if (rel == 1) pk1[i] = pv;
        else if (rel == 2) pkAll[i + off3[d]] = pv;
        else pkAll[i + off2[d + 1]] = pv;
    }
}

// ---------------- gather kernels (8 lanes/node, 16 nodes/block = 128 threads) ----------------
// Converged structure: all gather variants (16/8/4 lanes-per-node, deeper ILP, XCD x feature
// partitioning) land at ~6.3 TB/s effective gather BW = the 64B-granule random-access
// service ceiling. 128-thread blocks minimize dispatch-tail raggedness (round 7, +4us).

__global__ void agg_all_kernel(Agg4 a, const _Float16* __restrict__ Hh)
{
    int seg = blockIdx.y;
    int t = threadIdx.x;
    int node = blockIdx.x * 16 + (t >> 3);
    if (node >= a.s[seg].n) return;
    int o0 = (t & 7) * 8;
    const int* rows = a.s[seg].rows;
    int s = a.s[seg].off[node], e = a.s[seg].off[node + 1];
    float A[16] = {};
    int i = s;
    for (; i + 4 <= e; i += 4) {
        int r0 = rows[i], r1 = rows[i + 1], r2 = rows[i + 2], r3 = rows[i + 3];
        const _Float16* b0 = &Hh[(size_t)r0 * HID + o0];
        const _Float16* b1 = &Hh[(size_t)r1 * HID + o0];
        const _Float16* b2 = &Hh[(size_t)r2 * HID + o0];
        const _Float16* b3 = &Hh[(size_t)r3 * HID + o0];
        f16x8 x0a = *(const f16x8*)b0, x0b = *(const f16x8*)(b0 + 64);
        f16x8 x1a = *(const f16x8*)b1, x1b = *(const f16x8*)(b1 + 64);
        f16x8 x2a = *(const f16x8*)b2, x2b = *(const f16x8*)(b2 + 64);
        f16x8 x3a = *(const f16x8*)b3, x3b = *(const f16x8*)(b3 + 64);
#pragma unroll
        for (int j = 0; j < 8; j++) {
            A[j]     += ((float)x0a[j] + (float)x1a[j]) + ((float)x2a[j] + (float)x3a[j]);
            A[j + 8] += ((float)x0b[j] + (float)x1b[j]) + ((float)x2b[j] + (float)x3b[j]);
        }
    }
    for (; i < e; i++) {
        const _Float16* b = &Hh[(size_t)rows[i] * HID + o0];
        f16x8 xa = *(const f16x8*)b, xb = *(const f16x8*)(b + 64);
#pragma unroll
        for (int j = 0; j < 8; j++) { A[j] += (float)xa[j]; A[j + 8] += (float)xb[j]; }
    }
    float inv = (e > s) ? 1.0f / (float)(e - s) : 0.0f;
    f16x8 oa, ob;
#pragma unroll
    for (int j = 0; j < 8; j++) { oa[j] = (_Float16)(A[j] * inv); ob[j] = (_Float16)(A[j + 8] * inv); }
    _Float16* out = a.s[seg].out + (size_t)node * a.s[seg].ldo + o0;
    *(f16x8*)out = oa;
    *(f16x8*)(out + 64) = ob;
}

// base = fp16(0.1*Hh + genes: 0.9*dinv*sum_{v->g} h_v); z0 = Hh; vaccine rows -> dout (fixpoint)
__global__ void base_kernel(const _Float16* __restrict__ Hh, const int* __restrict__ r0rows,
                            const int* __restrict__ r0off, const float* __restrict__ dinv,
                            _Float16* __restrict__ base, _Float16* __restrict__ z0,
                            float* __restrict__ dout)
{
    int t = threadIdx.x;
    int node = blockIdx.x * 16 + (t >> 3);
    int o0 = (t & 7) * 8;
    size_t i0 = (size_t)node * HID + o0;
    size_t i1 = i0 + 64;
    f16x8 ha = *(const f16x8*)&Hh[i0];
    f16x8 hb = *(const f16x8*)&Hh[i1];
    if (node >= OV) {
        f32x4 oa0, oa1, ob0, ob1;
#pragma unroll
        for (int j = 0; j < 4; j++) {
            oa0[j] = (float)ha[j]; oa1[j] = (float)ha[j + 4];
            ob0[j] = (float)hb[j]; ob1[j] = (float)hb[j + 4];
        }
        *(f32x4*)&dout[i0] = oa0; *(f32x4*)&dout[i0 + 4] = oa1;
        *(f32x4*)&dout[i1] = ob0; *(f32x4*)&dout[i1 + 4] = ob1;
        return;
    }
    float A[16] = {};
    if (node < N_GENE) {
        int s = r0off[node], e = r0off[node + 1];
        int i = s;
        for (; i + 4 <= e; i += 4) {
            int r0 = r0rows[i], r1 = r0rows[i + 1], r2 = r0rows[i + 2], r3 = r0rows[i + 3];
            const _Float16* b0 = &Hh[(size_t)r0 * HID + o0];
            const _Float16* b1 = &Hh[(size_t)r1 * HID + o0];
            const _Float16* b2 = &Hh[(size_t)r2 * HID + o0];
            const _Float16* b3 = &Hh[(size_t)r3 * HID + o0];
            f16x8 x0a = *(const f16x8*)b0, x0b = *(const f16x8*)(b0 + 64);
            f16x8 x1a = *(const f16x8*)b1, x1b = *(const f16x8*)(b1 + 64);
            f16x8 x2a = *(const f16x8*)b2, x2b = *(const f16x8*)(b2 + 64);
            f16x8 x3a = *(const f16x8*)b3, x3b = *(const f16x8*)(b3 + 64);
#pragma unroll
            for (int j = 0; j < 8; j++) {
                A[j]     += ((float)x0a[j] + (float)x1a[j]) + ((float)x2a[j] + (float)x3a[j]);
                A[j + 8] += ((float)x0b[j] + (float)x1b[j]) + ((float)x2b[j] + (float)x3b[j]);
            }
        }
        for (; i < e; i++) {
            const _Float16* b = &Hh[(size_t)r0rows[i] * HID + o0];
            f16x8 xa = *(const f16x8*)b, xb = *(const f16x8*)(b + 64);
#pragma unroll
            for (int j = 0; j < 8; j++) { A[j] += (float)xa[j]; A[j + 8] += (float)xb[j]; }
        }
        float sc = 0.9f * dinv[node];
#pragma unroll
        for (int j = 0; j < 16; j++) A[j] *= sc;
    }
    f16x8 ba, bb;
#pragma unroll
    for (int j = 0; j < 8; j++) {
        ba[j] = (_Float16)(0.1f * (float)ha[j] + A[j]);
        bb[j] = (_Float16)(0.1f * (float)hb[j] + A[j + 8]);
    }
    *(f16x8*)&base[i0] = ba; *(f16x8*)&base[i1] = bb;
    *(f16x8*)&z0[i0] = ha;   *(f16x8*)&z0[i1] = hb;
}

__device__ __forceinline__ void gath8(const int2* __restrict__ pk, int s, int e, int o0,
                                      const _Float16* __restrict__ zin, float (&A)[16])
{
    int i = s;
    for (; i + 4 <= e; i += 4) {
        int2 p0 = pk[i], p1 = pk[i + 1], p2 = pk[i + 2], p3 = pk[i + 3];
        const _Float16* b0 = &zin[(size_t)p0.x * HID + o0];
        const _Float16* b1 = &zin[(size_t)p1.x * HID + o0];
        const _Float16* b2 = &zin[(size_t)p2.x * HID + o0];
        const _Float16* b3 = &zin[(size_t)p3.x * HID + o0];
        f16x8 x0a = *(const f16x8*)b0, x0b = *(const f16x8*)(b0 + 64);
        f16x8 x1a = *(const f16x8*)b1, x1b = *(const f16x8*)(b1 + 64);
        f16x8 x2a = *(const f16x8*)b2, x2b = *(const f16x8*)(b2 + 64);
        f16x8 x3a = *(const f16x8*)b3, x3b = *(const f16x8*)(b3 + 64);
        float w0 = __int_as_float(p0.y), w1 = __int_as_float(p1.y);
        float w2 = __int_as_float(p2.y), w3 = __int_as_float(p3.y);
#pragma unroll
        for (int j = 0; j < 8; j++) {
            A[j]     += ((float)x0a[j] * w0 + (float)x1a[j] * w1) + ((float)x2a[j] * w2 + (float)x3a[j] * w3);
            A[j + 8] += ((float)x0b[j] * w0 + (float)x1b[j] * w1) + ((float)x2b[j] * w2 + (float)x3b[j] * w3);
        }
    }
    for (; i < e; i++) {
        int2 p = pk[i];
        const _Float16* b = &zin[(size_t)p.x * HID + o0];
        f16x8 xa = *(const f16x8*)b, xb = *(const f16x8*)(b + 64);
        float w = __int_as_float(p.y);
#pragma unroll
        for (int j = 0; j < 8; j++) { A[j] += (float)xa[j] * w; A[j + 8] += (float)xb[j] * w; }
    }
}

// columns [0, 70000) in natural order; unified CSR (offA, pkAll), no branch.
template<typename OT>
__launch_bounds__(128)
__global__ void appnp_kernel(const _Float16* __restrict__ zin, OT* __restrict__ zout,
                             const _Float16* __restrict__ base,
                             const int* __restrict__ offA, const int2* __restrict__ pkAll,
                             const float* __restrict__ dinv)
{
    int t = threadIdx.x;
    int c = blockIdx.x * 16 + (t >> 3);
    if (c >= WLA_N) return;
    int o0 = (t & 7) * 8;
    float A[16] = {};
    gath8(pkAll, offA[c], offA[c + 1], o0, zin, A);
    float dc = dinv[c];
    float d2 = dc * dc;
    size_t i0 = (size_t)c * HID + o0;
    size_t i1 = i0 + 64;
    f16x8 za = *(const f16x8*)&zin[i0], zb = *(const f16x8*)&zin[i1];
    f16x8 ba = *(const f16x8*)&base[i0], bb = *(const f16x8*)&base[i1];
    float ra[8], rb[8];
#pragma unroll
    for (int j = 0; j < 8; j++) {
        ra[j] = 0.9f * (dc * A[j]     + d2 * (float)za[j]) + (float)ba[j];
        rb[j] = 0.9f * (dc * A[j + 8] + d2 * (float)zb[j]) + (float)bb[j];
    }
    if constexpr (sizeof(OT) == 2) {
        f16x8 oa, ob;
#pragma unroll
        for (int j = 0; j < 8; j++) { oa[j] = (_Float16)ra[j]; ob[j] = (_Float16)rb[j]; }
        *(f16x8*)&zout[i0] = oa;
        *(f16x8*)&zout[i1] = ob;
    } else {
        f32x4 oa0, oa1, ob0, ob1;
#pragma unroll
        for (int j = 0; j < 4; j++) {
            oa0[j] = ra[j]; oa1[j] = ra[j + 4];
            ob0[j] = rb[j]; ob1[j] = rb[j + 4];
        }
        *(f32x4*)&zout[i0] = oa0; *(f32x4*)&zout[i0 + 4] = oa1;
        *(f32x4*)&zout[i1] = ob0; *(f32x4*)&zout[i1 + 4] = ob1;
    }
}

// ---------------- weight prep (fp16 shadows) ----------------

__global__ void prep_all_kernel(const float* __restrict__ wg, const float* __restrict__ wp,
                                const float* __restrict__ wv,
                                _Float16* __restrict__ obg, _Float16* __restrict__ obp, _Float16* __restrict__ obv,
                                const float* __restrict__ wsl, const float* __restrict__ bsl,
                                const float* __restrict__ wsr,
                                _Float16* __restrict__ Wg0, _Float16* __restrict__ Wg1,
                                _Float16* __restrict__ Wp0, _Float16* __restrict__ Wp1,
                                float* __restrict__ bg0, float* __restrict__ bg1,
                                float* __restrict__ bp0, float* __restrict__ bp1)
{
    int y = blockIdx.y;
    int i = blockIdx.x * 256 + threadIdx.x;
    if (y == 0) {
        if (i < 32768) obg[i] = (_Float16)wg[i];
        if (i < 16384) obp[i] = (_Float16)wp[i];
        if (i < 8192)  obv[i] = (_Float16)wv[i];
        return;
    }
    int layer = y - 1;
    const float* WL = wsl + (size_t)layer * 4 * HID * HID;
    const float* WR = wsr + (size_t)layer * 4 * HID * HID;
    _Float16* Wg = layer ? Wg1 : Wg0;
    _Float16* Wp = layer ? Wp1 : Wp0;
    float* bg = layer ? bg1 : bg0;
    float* bp = layer ? bp1 : bp0;
    if (i < 128 * 512) {
        int nr = i >> 9, k = i & 511;
        float v;
        if (k < 128)      v = WL[0 * 16384 + nr * 128 + k];
        else if (k < 256) v = WL[2 * 16384 + nr * 128 + (k - 128)];
        else if (k < 384) v = WL[3 * 16384 + nr * 128 + (k - 256)];
        else {
            int kk = k - 384;
            v = WR[0 * 16384 + nr * 128 + kk] + WR[2 * 16384 + nr * 128 + kk] + WR[3 * 16384 + nr * 128 + kk];
        }
        Wg[i] = (_Float16)v;
    }
    if (i < 128 * 256) {
        int nr = i >> 8, k = i & 255;
        float v = (k < 128) ? WL[1 * 16384 + nr * 128 + k] : WR[1 * 16384 + nr * 128 + (k - 128)];
        Wp[i] = (_Float16)v;
    }
    if (i < 128) {
        const float* BL = bsl + (size_t)layer * 4 * HID;
        bg[i] = BL[0 * 128 + i] + BL[2 * 128 + i] + BL[3 * 128 + i];
        bp[i] = BL[1 * 128 + i];
    }
}

// ---------------- tiled MFMA GEMM, fp16, compile-time K (static unroll) ----------------

template<int KT, int K1, bool A_F32, bool SAGE>
__launch_bounds__(256)
__global__ void tgemm_kernel(const void* __restrict__ A1_, const _Float16* __restrict__ A2,
                             const _Float16* __restrict__ W, const float* __restrict__ bias,
                             float scale, _Float16* __restrict__ Hh, int M)
{
    __shared__ _Float16 lds[128 * 40];
    int t = threadIdx.x;
    int wave = t >> 6, lane = t & 63;
    int r = lane & 15, quad = lane >> 4;
    int mbase = blockIdx.x * 128 + wave * 32;
    int mm0 = min(mbase + r, M - 1);
    int mm1 = min(mbase + 16 + r, M - 1);
    const float* Af = (const float*)A1_;
    const _Float16* Ab = (const _Float16*)A1_;

    f32x4 acc[2][8];
#pragma unroll
    for (int s = 0; s < 2; s++)
#pragma unroll
        for (int n = 0; n < 8; n++) acc[s][n] = (f32x4){0.f, 0.f, 0.f, 0.f};

    int srow = t >> 1;
    int selt = (t & 1) * 16;

#pragma unroll
    for (int k0 = 0; k0 < KT; k0 += 32) {
        __syncthreads();
        {
            const _Float16* wsrc = W + (size_t)srow * KT + k0 + selt;
            f16x8 w0 = *(const f16x8*)wsrc;
            f16x8 w1 = *(const f16x8*)(wsrc + 8);
            *(f16x8*)&lds[srow * 40 + selt] = w0;
            *(f16x8*)&lds[srow * 40 + selt + 8] = w1;
        }
        f16x8 a0, a1;
        if constexpr (A_F32) {
            const float* p0 = Af + (size_t)mm0 * KT + k0 + quad * 8;
            const float* p1 = Af + (size_t)mm1 * KT + k0 + quad * 8;
            f32x4 x0 = *(const f32x4*)p0, x1 = *(const f32x4*)(p0 + 4);
            f32x4 y0 = *(const f32x4*)p1, y1 = *(const f32x4*)(p1 + 4);
#pragma unroll
            for (int j = 0; j < 4; j++) { a0[j] = (_Float16)x0[j]; a0[j + 4] = (_Float16)x1[j]; }
#pragma unroll
            for (int j = 0; j < 4; j++) { a1[j] = (_Float16)y0[j]; a1[j + 4] = (_Float16)y1[j]; }
        } else if (k0 < K1) {
            a0 = *(const f16x8*)(Ab + (size_t)mm0 * K1 + k0 + quad * 8);
            a1 = *(const f16x8*)(Ab + (size_t)mm1 * K1 + k0 + quad * 8);
        } else {
            a0 = *(const f16x8*)(A2 + (size_t)mm0 * 128 + (k0 - K1) + quad * 8);
            a1 = *(const f16x8*)(A2 + (size_t)mm1 * 128 + (k0 - K1) + quad * 8);
        }
        __syncthreads();
#pragma unroll
        for (int nt = 0; nt < 8; nt++) {
            f16x8 b = *(const f16x8*)&lds[(nt * 16 + r) * 40 + quad * 8];
            acc[0][nt] = __builtin_amdgcn_mfma_f32_16x16x32_f16(a0, b, acc[0][nt], 0, 0, 0);
            acc[1][nt] = __builtin_amdgcn_mfma_f32_16x16x32_f16(a1, b, acc[1][nt], 0, 0, 0);
        }
    }

#pragma unroll
    for (int sub = 0; sub < 2; sub++) {
#pragma unroll
        for (int nt = 0; nt < 8; nt++) {
            int n = nt * 16 + r;
            float bv = bias[n];
#pragma unroll
            for (int i = 0; i < 4; i++) {
                int row = mbase + sub * 16 + quad * 4 + i;
                if (row >= M) continue;
                size_t idx = (size_t)row * HID + n;
                float v;
                if constexpr (SAGE) v = fmaxf((float)Hh[idx] + (acc[sub][nt][i] + bv) * scale, 0.f);
                else                v = fmaxf(acc[sub][nt][i] + bv, 0.f);
                Hh[idx] = (_Float16)v;
            }
        }
    }
}

// ---------------- driver ----------------

extern "C" void kernel_launch(void* const* d_in, const int* in_sizes, int n_in,
                              void* d_out, int out_size, void* d_ws, size_t ws_size,
                              hipStream_t stream)
{
    (void)in_sizes; (void)n_in; (void)out_size; (void)ws_size;

    const float* x_gene = (const float*)d_in[0];
    const float* x_path = (const float*)d_in[1];
    const float* x_vacc = (const float*)d_in[2];
    const float* win_g  = (const float*)d_in[3];
    const float* bin_g  = (const float*)d_in[4];
    const float* win_p  = (const float*)d_in[5];
    const float* bin_p  = (const float*)d_in[6];
    const float* win_v  = (const float*)d_in[7];
    const float* bin_v  = (const float*)d_in[8];
    const float* wsl    = (const float*)d_in[9];
    const float* bsl    = (const float*)d_in[10];
    const float* wsr    = (const float*)d_in[11];
    const int* ei_tg  = (const int*)d_in[12];
    const int* ei_ing = (const int*)d_in[13];
    const int* ei_ct  = (const int*)d_in[14];
    const int* ei_ii  = (const int*)d_in[15];

    char* p = (char*)d_ws;
    auto alloc = [&](size_t b) { char* r = p; p += (b + 255) & ~((size_t)255); return r; };

    _Float16* Hh   = (_Float16*)alloc((size_t)N_TOT * HID * 2);
    _Float16* BASE = (_Float16*)alloc((size_t)OV * HID * 2);
    _Float16* Z1   = (_Float16*)alloc((size_t)OV * HID * 2);
    _Float16* Z2   = (_Float16*)alloc((size_t)OV * HID * 2);
    _Float16* AGG_G = (_Float16*)alloc((size_t)N_GENE * 384 * 2);
    _Float16* AGG_P = (_Float16*)alloc((size_t)N_PATH * 128 * 2);
    float* dinv   = (float*)alloc((size_t)N_TOT * 4);
    int* r_rows[4], *r_off[4];
    for (int r = 0; r < 4; r++) r_rows[r] = (int*)alloc((size_t)E_PER * 4);
    r_off[0] = (int*)alloc((size_t)(N_GENE + 1) * 4);
    r_off[1] = (int*)alloc((size_t)(N_PATH + 1) * 4);
    r_off[2] = (int*)alloc((size_t)(N_GENE + 1) * 4);
    r_off[3] = (int*)alloc((size_t)(N_GENE + 1) * 4);
    int* offA = (int*)alloc((size_t)(WLA_N + 1) * 4);
    int2* pkAll = (int2*)alloc((size_t)750000 * 8);   // [0,500000): merged gene cols; [500000,750000): pathway cols
    unsigned long long* kp0 = (unsigned long long*)alloc((size_t)4 * E_PER * 8);
    unsigned long long* kp1 = (unsigned long long*)alloc((size_t)4 * E_PER * 8);
    int* bh   = (int*)alloc((size_t)4 * NBLK_E * 256 * 4);
    int* tot  = (int*)alloc((size_t)4 * 256 * 4);
    int* basebuf = (int*)alloc((size_t)4 * 256 * 4);
    _Float16* wh_g = (_Float16*)alloc((size_t)HID * 256 * 2);
    _Float16* wh_p = (_Float16*)alloc((size_t)HID * 128 * 2);
    _Float16* wh_v = (_Float16*)alloc((size_t)HID * 64 * 2);
    _Float16* Wg[2]; _Float16* Wp[2]; float* bg[2]; float* bp[2];
    for (int l = 0; l < 2; l++) {
        Wg[l] = (_Float16*)alloc((size_t)128 * 512 * 2);
        Wp[l] = (_Float16*)alloc((size_t)128 * 256 * 2);
        bg[l] = (float*)alloc(128 * 4);
        bp[l] = (float*)alloc(128 * 4);
    }

    const int TB_G = (N_GENE + 127) / 128;
    const int TB_P = (N_PATH + 127) / 128;
    const int TB_V = (N_VACC + 127) / 128;

    prep_all_kernel<<<dim3(256, 3), 256, 0, stream>>>(win_g, win_p, win_v, wh_g, wh_p, wh_v,
                                                      wsl, bsl, wsr, Wg[0], Wg[1], Wp[0], Wp[1],
                                                      bg[0], bg[1], bp[0], bp[1]);

    // --- CSR build via MSD 2-pass bucket sort (no global atomics, no memset) ---
    Ei4 e4;
    e4.p[0] = ei_tg; e4.p[1] = ei_ing; e4.p[2] = ei_ct; e4.p[3] = ei_ii;
    p1hist_kernel<<<dim3(NBLK_E, 4), 256, 0, stream>>>(e4, bh);
    p1scan_kernel<<<dim3(256, 4), 256, 0, stream>>>(bh, tot);
    p1base_kernel<<<1, 256, 0, stream>>>(tot, basebuf);
    p1scatter_kernel<<<dim3(NBLK_E, 4), 256, 0, stream>>>(e4, bh, basebuf, kp1);
    p2sort_kernel<<<dim3(256, 4), 256, 0, stream>>>(kp1, kp0, tot, basebuf);

    Off4 op;
    op.p[0] = r_off[0]; op.p[1] = r_off[1]; op.p[2] = r_off[2]; op.p[3] = r_off[3];
    offbuild_kernel<<<dim3(NBLK_E, 4), 256, 0, stream>>>(kp0, op);

    dinv_kernel<<<(N_TOT + 255) / 256, 256, 0, stream>>>(r_off[0], r_off[1], r_off[2], r_off[3], dinv, offA);

    Off4 rp;
    rp.p[0] = r_rows[0]; rp.p[1] = r_rows[1]; rp.p[2] = r_rows[2]; rp.p[3] = r_rows[3];
    emit_kernel<<<dim3(NBLK_E, 4), 256, 0, stream>>>(kp0, dinv, r_off[2], r_off[3], rp, pkAll);

    // --- input projections (templated, static K) ---
    tgemm_kernel<256, 256, true, false><<<TB_G, 256, 0, stream>>>(x_gene, nullptr, wh_g, bin_g, 1.f, Hh, N_GENE);
    tgemm_kernel<128, 128, true, false><<<TB_P, 256, 0, stream>>>(x_path, nullptr, wh_p, bin_p, 1.f,
                                                                  Hh + (size_t)OP * HID, N_PATH);
    tgemm_kernel< 64,  64, true, false><<<TB_V, 256, 0, stream>>>(x_vacc, nullptr, wh_v, bin_v, 1.f,
                                                                  Hh + (size_t)OV * HID, N_VACC);

    // --- 2 hetero-SAGE layers ---
    Agg4 ag;
    ag.s[0] = {r_rows[0], r_off[0], AGG_G + 0,   384, N_GENE};
    ag.s[1] = {r_rows[2], r_off[2], AGG_G + 128, 384, N_GENE};
    ag.s[2] = {r_rows[3], r_off[3], AGG_G + 256, 384, N_GENE};
    ag.s[3] = {r_rows[1], r_off[1], AGG_P,       128, N_PATH};
    for (int l = 0; l < 2; l++) {
        agg_all_kernel<<<dim3((N_GENE + 15) / 16, 4), 128, 0, stream>>>(ag, Hh);

        tgemm_kernel<512, 384, false, true><<<TB_G, 256, 0, stream>>>(AGG_G, Hh, Wg[l], bg[l],
                                                                      1.0f / 3.0f, Hh, N_GENE);
        tgemm_kernel<256, 128, false, true><<<TB_P, 256, 0, stream>>>(AGG_P, Hh + (size_t)OP * HID, Wp[l], bp[l],
                                                                      1.0f, Hh + (size_t)OP * HID, N_PATH);
    }

    // --- APPNP over genes+pathways (vaccine rows fixpoint, written by base) ---
    float* dout = (float*)d_out;
    base_kernel<<<N_TOT / 16, 128, 0, stream>>>(Hh, r_rows[0], r_off[0], dinv, BASE, Z1, dout);

    const int GA = (WLA_N + 15) / 16;
    appnp_kernel<<<GA, 128, 0, stream>>>(Z1, Z2, BASE, offA, pkAll, dinv);
    appnp_kernel<<<GA, 128, 0, stream>>>(Z2, Z1, BASE, offA, pkAll, dinv);
    appnp_kernel<<<GA, 128, 0, stream>>>(Z1, Z2, BASE, offA, pkAll, dinv);
    appnp_kernel<<<GA, 128, 0, stream>>>(Z2, Z1, BASE, offA, pkAll, dinv);
    appnp_kernel<<<GA, 128, 0, stream>>>(Z1, Z2, BASE, offA, pkAll, dinv);
    appnp_kernel<<<GA, 128, 0, stream>>>(Z2, Z1, BASE, offA, pkAll, dinv);
    appnp_kernel<<<GA, 128, 0, stream>>>(Z1, Z2, BASE, offA, pkAll, dinv);
    appnp_kernel<<<GA, 128, 0, stream>>>(Z2, dout, BASE, offA, pkAll, dinv);
}